// Round 4
// baseline (541.632 us; speedup 1.0000x reference)
//
#include <hip/hip_runtime.h>

#define TLEN 1024
#define CDIM 256
#define NHEAD 4
#define HD 64
#define WIN_ 128
#define PADL 63
#define LWIN 1023
#define TPAD 1150
#define SW 32        // windows per strip: 32 strips x 4 heads x 2 variants = 256 blocks

typedef __attribute__((ext_vector_type(8))) short bf16x8;
typedef __attribute__((ext_vector_type(4))) float f32x4;

__device__ __forceinline__ int prow(int v, int t) {
  if (v == 0) return t;
  if (t < PADL || t >= PADL + TLEN) return t;
  int s = t - PADL;
  s = (s + (TLEN - 64)) & (TLEN - 1);   // roll(x, +64)
  return PADL + s;
}

__device__ __forceinline__ float hannf(int j) {
  return 0.5f * (1.0f - __cosf(6.283185307179586f * (float)j / 127.0f));
}

__device__ __forceinline__ float countf(int t) {
  int lo = t - 127; if (lo < 0) lo = 0;
  int hi = t;       if (hi > LWIN - 1) hi = LWIN - 1;
  return (float)(hi - lo + 1);
}

__device__ __forceinline__ unsigned short bfr(float f) {  // fp32 -> bf16 RTNE
  unsigned int u = __float_as_uint(f);
  u += 0x7FFFu + ((u >> 16) & 1u);
  return (unsigned short)(u >> 16);
}
// pack two f32 -> bf16x2 by truncation, single v_perm_b32
__device__ __forceinline__ unsigned int pk2t(float a, float b) {
  return __builtin_amdgcn_perm(__float_as_uint(b), __float_as_uint(a), 0x07060302u);
}
__device__ __forceinline__ float bfu(unsigned short u) {
  return __uint_as_float(((unsigned int)u) << 16);
}

// ---------------- LayerNorm -> bf16 ----------------
__global__ void k_ln(const float* __restrict__ x, const float* __restrict__ g,
                     const float* __restrict__ b, unsigned short* __restrict__ lnbf) {
  int wv = threadIdx.x >> 6, lane = threadIdx.x & 63;
  int r = blockIdx.x * 4 + wv;
  float4 v = ((const float4*)(x + (size_t)r * CDIM))[lane];
  float s = v.x + v.y + v.z + v.w;
  float q = v.x * v.x + v.y * v.y + v.z * v.z + v.w * v.w;
  #pragma unroll
  for (int m = 32; m >= 1; m >>= 1) { s += __shfl_xor(s, m); q += __shfl_xor(q, m); }
  float mu = s * (1.0f / 256.0f);
  float var = q * (1.0f / 256.0f) - mu * mu;
  float rs = rsqrtf(var + 1e-5f);
  float4 gg = ((const float4*)g)[lane];
  float4 bb = ((const float4*)b)[lane];
  uint2 o;
  o.x = (unsigned int)bfr((v.x - mu) * rs * gg.x + bb.x) |
        ((unsigned int)bfr((v.y - mu) * rs * gg.y + bb.y) << 16);
  o.y = (unsigned int)bfr((v.z - mu) * rs * gg.z + bb.z) |
        ((unsigned int)bfr((v.w - mu) * rs * gg.w + bb.w) << 16);
  ((uint2*)(lnbf + (size_t)r * CDIM))[lane] = o;
}

// ---------------- cast in_proj_w -> bf16 ----------------
__global__ void k_castw(const float* __restrict__ W, unsigned short* __restrict__ Wb) {
  int i = blockIdx.x * 256 + threadIdx.x;   // 8 elems each
  const float4* src = (const float4*)W;
  float4 a = src[2 * i], b = src[2 * i + 1];
  uint4 o;
  o.x = (unsigned int)bfr(a.x) | ((unsigned int)bfr(a.y) << 16);
  o.y = (unsigned int)bfr(a.z) | ((unsigned int)bfr(a.w) << 16);
  o.z = (unsigned int)bfr(b.x) | ((unsigned int)bfr(b.y) << 16);
  o.w = (unsigned int)bfr(b.z) | ((unsigned int)bfr(b.w) << 16);
  ((uint4*)Wb)[i] = o;
}

// ---------------- P projection via MFMA: P[63+s][e] = ln[s]·W[e] ----------------
__launch_bounds__(512, 1)
__global__ void k_proj(const unsigned short* __restrict__ lnbf,
                       const unsigned short* __restrict__ Wb,
                       unsigned short* __restrict__ Pbf) {
  const int tid = threadIdx.x;
  const int lane = tid & 63, wv = tid >> 6;
  const int li16 = lane & 15, q4 = lane >> 4;
  const int ws = wv & 1, we = wv >> 1;
  const int s0 = blockIdx.x * 128 + ws * 64;
  const int e0 = blockIdx.y * 128 + we * 32;

  f32x4 acc[4][2];
  #pragma unroll
  for (int it = 0; it < 4; ++it)
    #pragma unroll
    for (int et = 0; et < 2; ++et) acc[it][et] = (f32x4){0.f, 0.f, 0.f, 0.f};

  #pragma unroll
  for (int ks = 0; ks < 8; ++ks) {
    bf16x8 Af[4], Bf[2];
    #pragma unroll
    for (int it = 0; it < 4; ++it)
      Af[it] = *(const bf16x8*)(lnbf + (size_t)(s0 + 16 * it + li16) * 256 + ks * 32 + q4 * 8);
    #pragma unroll
    for (int et = 0; et < 2; ++et)
      Bf[et] = *(const bf16x8*)(Wb + (size_t)(e0 + 16 * et + li16) * 256 + ks * 32 + q4 * 8);
    #pragma unroll
    for (int it = 0; it < 4; ++it)
      #pragma unroll
      for (int et = 0; et < 2; ++et)
        acc[it][et] = __builtin_amdgcn_mfma_f32_16x16x32_bf16(Af[it], Bf[et], acc[it][et], 0, 0, 0);
  }
  #pragma unroll
  for (int it = 0; it < 4; ++it)
    #pragma unroll
    for (int et = 0; et < 2; ++et)
      #pragma unroll
      for (int r = 0; r < 4; ++r) {
        int srow = s0 + 16 * it + 4 * q4 + r;
        int e = e0 + 16 * et + li16;
        Pbf[(size_t)(PADL + srow) * 768 + e] = bfr(acc[it][et][r]);
      }
}

// ---------------- merged M = proj_w @ out_w (bf16, row-major); vbv = proj_w·out_b ----------------
__global__ void k_mmat(const float* __restrict__ pw, const float* __restrict__ ow,
                       const float* __restrict__ ob, unsigned short* __restrict__ Mtb,
                       float* __restrict__ vbv) {
  __shared__ float pr[256];
  __shared__ float red[256];
  int e = blockIdx.x, tid = threadIdx.x;
  pr[tid] = pw[(size_t)e * CDIM + tid];
  __syncthreads();
  float a0 = 0.f, a1 = 0.f, a2 = 0.f, a3 = 0.f;
  for (int m = 0; m < 256; m += 4) {
    a0 += pr[m] * ow[(size_t)m * CDIM + tid];
    a1 += pr[m + 1] * ow[(size_t)(m + 1) * CDIM + tid];
    a2 += pr[m + 2] * ow[(size_t)(m + 2) * CDIM + tid];
    a3 += pr[m + 3] * ow[(size_t)(m + 3) * CDIM + tid];
  }
  Mtb[(size_t)e * CDIM + tid] = bfr((a0 + a1) + (a2 + a3));
  red[tid] = pr[tid] * ob[tid];
  __syncthreads();
  for (int s = 128; s > 0; s >>= 1) { if (tid < s) red[tid] += red[tid + s]; __syncthreads(); }
  if (tid == 0) vbv[e] = red[0];
}

// ---------------- V window staging: global -> LDS transposed ----------------
__device__ __forceinline__ void stage_v(const unsigned short* __restrict__ Pbf,
                                        unsigned short* vt, int v, int hd,
                                        int trow0, int tid) {
  int j = tid & 127, dgsel = tid >> 7;
  int row = prow(v, trow0 + j);
  const unsigned short* base = Pbf + (size_t)row * 768 + 512 + hd * 64;
  #pragma unroll
  for (int pass = 0; pass < 2; ++pass) {
    int dg = dgsel + 4 * pass;
    uint4 a = *(const uint4*)(base + dg * 8);
    int d0 = dg * 8;
    vt[(d0 + 0) * 128 + (j ^ 0)]  = (unsigned short)(a.x & 0xFFFF);
    vt[(d0 + 1) * 128 + (j ^ 8)]  = (unsigned short)(a.x >> 16);
    vt[(d0 + 2) * 128 + (j ^ 16)] = (unsigned short)(a.y & 0xFFFF);
    vt[(d0 + 3) * 128 + (j ^ 24)] = (unsigned short)(a.y >> 16);
    vt[(d0 + 4) * 128 + (j ^ 32)] = (unsigned short)(a.z & 0xFFFF);
    vt[(d0 + 5) * 128 + (j ^ 40)] = (unsigned short)(a.z >> 16);
    vt[(d0 + 6) * 128 + (j ^ 48)] = (unsigned short)(a.w & 0xFFFF);
    vt[(d0 + 7) * 128 + (j ^ 56)] = (unsigned short)(a.w >> 16);
  }
}

// ---------------- MFMA attention, strip-span formulation ----------------
__launch_bounds__(512, 2)
__global__ void k_attn(const unsigned short* __restrict__ Pbf, const float* __restrict__ ipb,
                       float* __restrict__ accg) {
  __shared__ __align__(16) unsigned short Pq[159 * 64];   // raw Q-proj span, swizzle d^((t&7)<<3)
  __shared__ __align__(16) unsigned short Pk[159 * 64];
  __shared__ __align__(16) unsigned short Vt[2][64 * 128]; // V^T window, swizzle j^((d&7)<<3)
  __shared__ __align__(16) unsigned short Ab[128 * 128];   // A'' window, swizzle j^((i&7)<<3)
  __shared__ float accs[159 * 65];
  __shared__ float hth[128];
  __shared__ float bB[160];
  __shared__ float bqS[64];

  const int strip = blockIdx.x, hd = blockIdx.y, v = blockIdx.z;
  const int l0 = strip * SW;
  const int nw = (SW < LWIN - l0) ? SW : (LWIN - l0);
  const int span = nw - 1 + WIN_;
  const int tid = threadIdx.x;
  const int lane = tid & 63, wv = tid >> 6;
  const int li16 = lane & 15, q4 = lane >> 4;
  const int iw = 16 * wv + li16;          // this thread's output row i (window-local)

  for (int i = tid; i < 159 * 65; i += 512) accs[i] = 0.0f;
  if (tid < 128) hth[tid] = hannf(tid);
  if (tid < 64) bqS[tid] = ipb[hd * 64 + tid];
  // stage raw Pq/Pk spans
  for (int i = tid; i < span * 8; i += 512) {
    int t = i >> 3, dg = i & 7;
    int row = prow(v, l0 + t);
    const unsigned short* src = Pbf + (size_t)row * 768 + hd * 64;
    uint4 q = *(const uint4*)(src + dg * 8);
    uint4 k = *(const uint4*)(src + 256 + dg * 8);
    int off = (dg * 8) ^ ((t & 7) << 3);
    *(uint4*)&Pq[t * 64 + off] = q;
    *(uint4*)&Pk[t * 64 + off] = k;
  }
  __syncthreads();

  // bias-dot array b(t) = bq·Pk(t)   (aA/c dropped: constant per softmax row)
  for (int p = tid; p < span; p += 512) {
    float b = 0.0f;
    int sw = (p & 7) << 3;
    for (int d = 0; d < 64; ++d) b += bqS[d] * bfu(Pk[p * 64 + (d ^ sw)]);
    bB[p] = b;
  }
  stage_v(Pbf, &Vt[0][0], v, hd, l0, tid);
  __syncthreads();

  // per-thread hann registers: hj8[m] = h(j)/8 at j = 16*(m>>2) + 4*q4 + (m&3)
  float hj8[32];
  #pragma unroll
  for (int tj = 0; tj < 8; ++tj)
    #pragma unroll
    for (int r = 0; r < 4; ++r) hj8[tj * 4 + r] = hth[16 * tj + 4 * q4 + r] * 0.125f;
  const float h_i = hth[iw];

  #pragma unroll 1
  for (int w = 0; w < nw; ++w) {
    // ---- S^T[j][i] = sum_d Pk[w+j][d] * Pq[w+i][d]  (raw Gram) ----
    bf16x8 Qf[2];
    {
      int t = w + iw, sw = (t & 7) << 3;
      Qf[0] = *(bf16x8*)&Pq[t * 64 + (0  ^ sw) + 8 * q4];
      Qf[1] = *(bf16x8*)&Pq[t * 64 + (32 ^ sw) + 8 * q4];
    }
    f32x4 S[8];
    #pragma unroll
    for (int tj = 0; tj < 8; ++tj) S[tj] = (f32x4){0.f, 0.f, 0.f, 0.f};
    #pragma unroll
    for (int tj = 0; tj < 8; ++tj) {
      int t = w + 16 * tj + li16, sw = (t & 7) << 3;
      bf16x8 Kf0 = *(bf16x8*)&Pk[t * 64 + (0  ^ sw) + 8 * q4];
      bf16x8 Kf1 = *(bf16x8*)&Pk[t * 64 + (32 ^ sw) + 8 * q4];
      S[tj] = __builtin_amdgcn_mfma_f32_16x16x32_bf16(Kf0, Qf[0], S[tj], 0, 0, 0);
      S[tj] = __builtin_amdgcn_mfma_f32_16x16x32_bf16(Kf1, Qf[1], S[tj], 0, 0, 0);
    }

    // ---- softmax over j (no max-subtract: |s| << 80 for these inputs) ----
    float sum = 0.0f;
    #pragma unroll
    for (int tj = 0; tj < 8; ++tj)
      #pragma unroll
      for (int r = 0; r < 4; ++r) {
        int j = 16 * tj + 4 * q4 + r;
        float e = __expf(hj8[tj * 4 + r] * fmaf(h_i, S[tj][r], bB[w + j]));
        S[tj][r] = e;
        sum += e;
      }
    sum += __shfl_xor(sum, 16);
    sum += __shfl_xor(sum, 32);
    const float sc = 8.0f / sum;   // applied at accumulate; recovers h(j) scale too

    // ---- A''[i][j] = e * h(j)/8, bf16-trunc into Ab (wave-private rows) ----
    {
      int sw = (iw & 7) << 3;
      #pragma unroll
      for (int tj = 0; tj < 8; ++tj) {
        uint2 o;
        o.x = pk2t(S[tj][0] * hj8[tj * 4 + 0], S[tj][1] * hj8[tj * 4 + 1]);
        o.y = pk2t(S[tj][2] * hj8[tj * 4 + 2], S[tj][3] * hj8[tj * 4 + 3]);
        *(uint2*)&Ab[iw * 128 + ((16 * tj + 4 * q4) ^ sw)] = o;
      }
    }

    // ---- O^T[d][i] = sum_j Vt[d][j] * A''[i][j] ----
    f32x4 O[4];
    #pragma unroll
    for (int mt = 0; mt < 4; ++mt) O[mt] = (f32x4){0.f, 0.f, 0.f, 0.f};
    const unsigned short* vt = &Vt[w & 1][0];
    {
      int swi = (iw & 7) << 3;
      #pragma unroll
      for (int ks = 0; ks < 4; ++ks) {
        bf16x8 Bf = *(bf16x8*)&Ab[iw * 128 + ((32 * ks + 8 * q4) ^ swi)];
        #pragma unroll
        for (int mt = 0; mt < 4; ++mt) {
          int d = 16 * mt + li16;
          bf16x8 Af = *(bf16x8*)&vt[d * 128 + ((32 * ks + 8 * q4) ^ ((d & 7) << 3))];
          O[mt] = __builtin_amdgcn_mfma_f32_16x16x32_bf16(Af, Bf, O[mt], 0, 0, 0);
        }
      }
    }

    // ---- accumulate O^T * sc into strip overlap-add buffer (ds_add RMW) ----
    {
      int p = w + iw;
      #pragma unroll
      for (int mt = 0; mt < 4; ++mt)
        #pragma unroll
        for (int r = 0; r < 4; ++r)
          atomicAdd(&accs[p * 65 + 16 * mt + 4 * q4 + r], O[mt][r] * sc);
    }

    if (w + 1 < nw) stage_v(Pbf, &Vt[(w + 1) & 1][0], v, hd, l0 + w + 1, tid);
    __syncthreads();
  }

  // ---- epilogue: + cnt*bv, atomic into global ----
  float* av = accg + (size_t)v * TPAD * CDIM;
  for (int i = tid; i < span * 64; i += 512) {
    int p = i >> 6, dd = i & 63;
    int lo = p - 127; if (lo < 0) lo = 0;
    int hi = p; if (hi > nw - 1) hi = nw - 1;
    float cnt = (float)(hi - lo + 1);
    float bvd = ipb[512 + hd * 64 + dd];
    atomicAdd(&av[(size_t)(l0 + p) * CDIM + hd * 64 + dd],
              accs[p * 65 + dd] + cnt * bvd);
  }
}

// ---------------- combine variants + merged projection (MFMA) ----------------
__launch_bounds__(512, 1)
__global__ void k_comb(const float* __restrict__ accg, const unsigned short* __restrict__ Mtb,
                       const float* __restrict__ vbv, const float* __restrict__ pb,
                       float* __restrict__ z, float* __restrict__ msum) {
  __shared__ __align__(16) unsigned short Ub[128 * 264];  // u-tile bf16, padded stride
  __shared__ float cfA[128], cfB[128], bscL[128];
  __shared__ float msB[256];
  const int tid = threadIdx.x;
  const int lane = tid & 63, wv = tid >> 6;
  const int li16 = lane & 15, q4 = lane >> 4;
  const int tw = wv & 1, ew = wv >> 1;
  const int t0 = blockIdx.x * 128;
  const int e0 = blockIdx.y * 128;

  if (tid < 128) {
    int s = t0 + tid;
    float c0 = countf(PADL + s);
    float c1 = countf(PADL + ((s + 64) & (TLEN - 1)));
    float fA = 0.5f / (c0 + 1e-6f), fB = 0.5f / (c1 + 1e-6f);
    cfA[tid] = fA; cfB[tid] = fB;
    bscL[tid] = c0 * fA + c1 * fB;
  }
  if (tid < 256) msB[tid] = 0.0f;
  __syncthreads();

  // build u-tile: u = 0.5*(a0/c0 + a1/c1), bf16
  for (int i = tid; i < 128 * 128; i += 512) {
    int rr = i >> 7, c2 = (i & 127) * 2;
    int s = t0 + rr;
    int s1 = (s + 64) & (TLEN - 1);
    float2 a0 = *(const float2*)&accg[(size_t)(PADL + s) * CDIM + c2];
    float2 a1 = *(const float2*)&accg[(size_t)TPAD * CDIM + (size_t)(PADL + s1) * CDIM + c2];
    float fA = cfA[rr], fB = cfB[rr];
    *(unsigned int*)&Ub[rr * 264 + c2] =
        pk2t(a0.x * fA + a1.x * fB, a0.y * fA + a1.y * fB);
  }
  __syncthreads();

  // GEMM: z[t][e] = sum_c u[t][c] * M[e][c]
  f32x4 acc[4][2];
  #pragma unroll
  for (int it = 0; it < 4; ++it)
    #pragma unroll
    for (int et = 0; et < 2; ++et) acc[it][et] = (f32x4){0.f, 0.f, 0.f, 0.f};
  #pragma unroll
  for (int ks = 0; ks < 8; ++ks) {
    bf16x8 Af[4], Bf[2];
    #pragma unroll
    for (int it = 0; it < 4; ++it)
      Af[it] = *(bf16x8*)&Ub[(tw * 64 + 16 * it + li16) * 264 + ks * 32 + q4 * 8];
    #pragma unroll
    for (int et = 0; et < 2; ++et)
      Bf[et] = *(const bf16x8*)(Mtb + (size_t)(e0 + ew * 32 + 16 * et + li16) * 256 + ks * 32 + q4 * 8);
    #pragma unroll
    for (int it = 0; it < 4; ++it)
      #pragma unroll
      for (int et = 0; et < 2; ++et)
        acc[it][et] = __builtin_amdgcn_mfma_f32_16x16x32_bf16(Af[it], Bf[et], acc[it][et], 0, 0, 0);
  }

  // epilogue + msum
  #pragma unroll
  for (int et = 0; et < 2; ++et) {
    int e = e0 + ew * 32 + 16 * et + li16;
    float vbe = vbv[e], pbe = pb[e];
    float part = 0.0f;
    #pragma unroll
    for (int it = 0; it < 4; ++it)
      #pragma unroll
      for (int r = 0; r < 4; ++r) {
        int rloc = tw * 64 + 16 * it + 4 * q4 + r;
        float val = acc[it][et][r] + bscL[rloc] * vbe + pbe;
        z[(size_t)(t0 + rloc) * CDIM + e] = val;
        part += val;
      }
    atomicAdd(&msB[e - e0 + (e0 & 128)], part);   // msB indexed 0..255 across both e-blocks? (e0 is 0 or 128)
  }
  __syncthreads();
  if (tid < 128) atomicAdd(&msum[e0 + tid], msB[tid + (e0 & 128)]);
}

// ---------------- SE gate (parallel) ----------------
__global__ void k_se(const float* __restrict__ msum, const float* __restrict__ w1,
                     const float* __restrict__ w2, float* __restrict__ gate) {
  __shared__ float red2[16][4];
  __shared__ float s1[16];
  int tid = threadIdx.x;
  int lane = tid & 63, wv = tid >> 6;
  float sm = msum[tid] * (1.0f / 1024.0f);
  #pragma unroll
  for (int r = 0; r < 16; ++r) {
    float v = sm * w1[(size_t)r * 256 + tid];
    #pragma unroll
    for (int m = 32; m >= 1; m >>= 1) v += __shfl_xor(v, m);
    if (lane == 0) red2[r][wv] = v;
  }
  __syncthreads();
  if (tid < 16) {
    float a = red2[tid][0] + red2[tid][1] + red2[tid][2] + red2[tid][3];
    s1[tid] = fmaxf(a, 0.0f);
  }
  __syncthreads();
  float gacc = 0.0f;
  #pragma unroll
  for (int i = 0; i < 16; ++i) gacc += s1[i] * w2[(size_t)tid * 16 + i];
  gate[tid] = 1.0f / (1.0f + __expf(-gacc));
}

// ---------------- out = x + z * gate ----------------
__global__ void k_final(const float* __restrict__ x, const float* __restrict__ z,
                        const float* __restrict__ gate, float* __restrict__ out) {
  int i = blockIdx.x * 256 + threadIdx.x;
  float4 xv = ((const float4*)x)[i];
  float4 zv = ((const float4*)z)[i];
  float4 gv = ((const float4*)gate)[i & 63];
  float4 o;
  o.x = xv.x + zv.x * gv.x;
  o.y = xv.y + zv.y * gv.y;
  o.z = xv.z + zv.z * gv.z;
  o.w = xv.w + zv.w * gv.w;
  ((float4*)out)[i] = o;
}

extern "C" void kernel_launch(void* const* d_in, const int* in_sizes, int n_in,
                              void* d_out, int out_size, void* d_ws, size_t ws_size,
                              hipStream_t stream) {
  const float* x   = (const float*)d_in[0];
  const float* lng = (const float*)d_in[1];
  const float* lnb = (const float*)d_in[2];
  const float* ipw = (const float*)d_in[3];
  const float* ipb = (const float*)d_in[4];
  const float* ow  = (const float*)d_in[5];
  const float* ob  = (const float*)d_in[6];
  const float* pw  = (const float*)d_in[7];
  const float* pb  = (const float*)d_in[8];
  const float* w1  = (const float*)d_in[9];
  const float* w2  = (const float*)d_in[10];
  float* out = (float*)d_out;

  float* ws = (float*)d_ws;
  unsigned short* lnbf = (unsigned short*)ws;             // 1024*256 bf16 = 131072 f
  unsigned short* Wb   = (unsigned short*)(ws + 131072);  // 768*256  bf16 = 98304 f
  unsigned short* Pbf  = (unsigned short*)(ws + 229376);  // 1150*768 bf16 = 441600 f
  float* accg = ws + 229376 + 441600;                     // 2*1150*256 = 588800 f
  unsigned short* Mtb = (unsigned short*)(accg + 588800); // 256*256 bf16 = 32768 f
  float* vbv  = accg + 588800 + 32768;                    // 256
  float* z    = vbv + 256;                                // 262144
  float* msum = z + 262144;                               // 256
  float* gate = msum + 256;                               // 256

  hipMemsetAsync(Pbf, 0, (size_t)TPAD * 768 * sizeof(unsigned short), stream);
  hipMemsetAsync(accg, 0, (size_t)2 * TPAD * CDIM * sizeof(float), stream);
  hipMemsetAsync(msum, 0, CDIM * sizeof(float), stream);

  k_ln<<<dim3(TLEN / 4), dim3(256), 0, stream>>>(x, lng, lnb, lnbf);
  k_castw<<<dim3(96), dim3(256), 0, stream>>>(ipw, Wb);
  k_proj<<<dim3(8, 6), dim3(512), 0, stream>>>(lnbf, Wb, Pbf);
  k_mmat<<<dim3(256), dim3(256), 0, stream>>>(pw, ow, ob, Mtb, vbv);
  k_attn<<<dim3(32, NHEAD, 2), dim3(512), 0, stream>>>(Pbf, ipb, accg);
  k_comb<<<dim3(8, 2), dim3(512), 0, stream>>>(accg, Mtb, vbv, pb, z, msum);
  k_se<<<dim3(1), dim3(256), 0, stream>>>(msum, w1, w2, gate);
  k_final<<<dim3(256), dim3(256), 0, stream>>>(x, z, gate, out);
}

// Round 7
// 223.927 us; speedup vs baseline: 2.4188x; 2.4188x over previous
//
#include <hip/hip_runtime.h>

#define TLEN 1024
#define CDIM 256
#define NHEAD 4
#define HD 64
#define WIN_ 128
#define PADL 63
#define LWIN 1023
#define TPAD 1150
#define SW 32        // windows per strip: 32 strips x 4 heads x 2 variants = 256 blocks

typedef __attribute__((ext_vector_type(8))) short bf16x8;
typedef __attribute__((ext_vector_type(4))) float f32x4;

__device__ __forceinline__ int prow(int v, int t) {
  if (v == 0) return t;
  if (t < PADL || t >= PADL + TLEN) return t;
  int s = t - PADL;
  s = (s + (TLEN - 64)) & (TLEN - 1);   // roll(x, +64)
  return PADL + s;
}

__device__ __forceinline__ float hannf(int j) {
  return 0.5f * (1.0f - __cosf(6.283185307179586f * (float)j / 127.0f));
}

__device__ __forceinline__ float countf(int t) {
  int lo = t - 127; if (lo < 0) lo = 0;
  int hi = t;       if (hi > LWIN - 1) hi = LWIN - 1;
  return (float)(hi - lo + 1);
}

__device__ __forceinline__ unsigned short bfr(float f) {  // fp32 -> bf16 RTNE
  unsigned int u = __float_as_uint(f);
  u += 0x7FFFu + ((u >> 16) & 1u);
  return (unsigned short)(u >> 16);
}
// pack two f32 -> bf16x2 by truncation, single v_perm_b32
__device__ __forceinline__ unsigned int pk2t(float a, float b) {
  return __builtin_amdgcn_perm(__float_as_uint(b), __float_as_uint(a), 0x07060302u);
}
__device__ __forceinline__ float bfu(unsigned short u) {
  return __uint_as_float(((unsigned int)u) << 16);
}

// ---------------- LayerNorm -> bf16 ----------------
__global__ void k_ln(const float* __restrict__ x, const float* __restrict__ g,
                     const float* __restrict__ b, unsigned short* __restrict__ lnbf) {
  int wv = threadIdx.x >> 6, lane = threadIdx.x & 63;
  int r = blockIdx.x * 4 + wv;
  float4 v = ((const float4*)(x + (size_t)r * CDIM))[lane];
  float s = v.x + v.y + v.z + v.w;
  float q = v.x * v.x + v.y * v.y + v.z * v.z + v.w * v.w;
  #pragma unroll
  for (int m = 32; m >= 1; m >>= 1) { s += __shfl_xor(s, m); q += __shfl_xor(q, m); }
  float mu = s * (1.0f / 256.0f);
  float var = q * (1.0f / 256.0f) - mu * mu;
  float rs = rsqrtf(var + 1e-5f);
  float4 gg = ((const float4*)g)[lane];
  float4 bb = ((const float4*)b)[lane];
  uint2 o;
  o.x = (unsigned int)bfr((v.x - mu) * rs * gg.x + bb.x) |
        ((unsigned int)bfr((v.y - mu) * rs * gg.y + bb.y) << 16);
  o.y = (unsigned int)bfr((v.z - mu) * rs * gg.z + bb.z) |
        ((unsigned int)bfr((v.w - mu) * rs * gg.w + bb.w) << 16);
  ((uint2*)(lnbf + (size_t)r * CDIM))[lane] = o;
}

// ---------------- cast in_proj_w -> bf16 ----------------
__global__ void k_castw(const float* __restrict__ W, unsigned short* __restrict__ Wb) {
  int i = blockIdx.x * 256 + threadIdx.x;   // 8 elems each
  const float4* src = (const float4*)W;
  float4 a = src[2 * i], b = src[2 * i + 1];
  uint4 o;
  o.x = (unsigned int)bfr(a.x) | ((unsigned int)bfr(a.y) << 16);
  o.y = (unsigned int)bfr(a.z) | ((unsigned int)bfr(a.w) << 16);
  o.z = (unsigned int)bfr(b.x) | ((unsigned int)bfr(b.y) << 16);
  o.w = (unsigned int)bfr(b.z) | ((unsigned int)bfr(b.w) << 16);
  ((uint4*)Wb)[i] = o;
}

// ---------------- P projection via MFMA: P[63+s][e] = ln[s]·W[e] ----------------
__launch_bounds__(512, 1)
__global__ void k_proj(const unsigned short* __restrict__ lnbf,
                       const unsigned short* __restrict__ Wb,
                       unsigned short* __restrict__ Pbf) {
  const int tid = threadIdx.x;
  const int lane = tid & 63, wv = tid >> 6;
  const int li16 = lane & 15, q4 = lane >> 4;
  const int ws = wv & 1, we = wv >> 1;
  const int s0 = blockIdx.x * 128 + ws * 64;
  const int e0 = blockIdx.y * 128 + we * 32;

  f32x4 acc[4][2];
  #pragma unroll
  for (int it = 0; it < 4; ++it)
    #pragma unroll
    for (int et = 0; et < 2; ++et) acc[it][et] = (f32x4){0.f, 0.f, 0.f, 0.f};

  #pragma unroll
  for (int ks = 0; ks < 8; ++ks) {
    bf16x8 Af[4], Bf[2];
    #pragma unroll
    for (int it = 0; it < 4; ++it)
      Af[it] = *(const bf16x8*)(lnbf + (size_t)(s0 + 16 * it + li16) * 256 + ks * 32 + q4 * 8);
    #pragma unroll
    for (int et = 0; et < 2; ++et)
      Bf[et] = *(const bf16x8*)(Wb + (size_t)(e0 + 16 * et + li16) * 256 + ks * 32 + q4 * 8);
    #pragma unroll
    for (int it = 0; it < 4; ++it)
      #pragma unroll
      for (int et = 0; et < 2; ++et)
        acc[it][et] = __builtin_amdgcn_mfma_f32_16x16x32_bf16(Af[it], Bf[et], acc[it][et], 0, 0, 0);
  }
  #pragma unroll
  for (int it = 0; it < 4; ++it)
    #pragma unroll
    for (int et = 0; et < 2; ++et)
      #pragma unroll
      for (int r = 0; r < 4; ++r) {
        int srow = s0 + 16 * it + 4 * q4 + r;
        int e = e0 + 16 * et + li16;
        Pbf[(size_t)(PADL + srow) * 768 + e] = bfr(acc[it][et][r]);
      }
}

// ---------------- merged M = proj_w @ out_w (bf16, row-major); vbv = proj_w·out_b ----------------
__global__ void k_mmat(const float* __restrict__ pw, const float* __restrict__ ow,
                       const float* __restrict__ ob, unsigned short* __restrict__ Mtb,
                       float* __restrict__ vbv) {
  __shared__ float pr[256];
  __shared__ float red[256];
  int e = blockIdx.x, tid = threadIdx.x;
  pr[tid] = pw[(size_t)e * CDIM + tid];
  __syncthreads();
  float a0 = 0.f, a1 = 0.f, a2 = 0.f, a3 = 0.f;
  for (int m = 0; m < 256; m += 4) {
    a0 += pr[m] * ow[(size_t)m * CDIM + tid];
    a1 += pr[m + 1] * ow[(size_t)(m + 1) * CDIM + tid];
    a2 += pr[m + 2] * ow[(size_t)(m + 2) * CDIM + tid];
    a3 += pr[m + 3] * ow[(size_t)(m + 3) * CDIM + tid];
  }
  Mtb[(size_t)e * CDIM + tid] = bfr((a0 + a1) + (a2 + a3));
  red[tid] = pr[tid] * ob[tid];
  __syncthreads();
  for (int s = 128; s > 0; s >>= 1) { if (tid < s) red[tid] += red[tid + s]; __syncthreads(); }
  if (tid == 0) vbv[e] = red[0];
}

// ---------------- V window staging: global -> LDS transposed (scalar, round-4-proven) ----------------
__device__ __forceinline__ void stage_v(const unsigned short* __restrict__ Pbf,
                                        unsigned short* vt, int v, int hd,
                                        int trow0, int tid) {
  int j = tid & 127, dgsel = tid >> 7;
  int row = prow(v, trow0 + j);
  const unsigned short* base = Pbf + (size_t)row * 768 + 512 + hd * 64;
  #pragma unroll
  for (int pass = 0; pass < 2; ++pass) {
    int dg = dgsel + 4 * pass;
    uint4 a = *(const uint4*)(base + dg * 8);
    int d0 = dg * 8;
    vt[(d0 + 0) * 128 + (j ^ 0)]  = (unsigned short)(a.x & 0xFFFF);
    vt[(d0 + 1) * 128 + (j ^ 8)]  = (unsigned short)(a.x >> 16);
    vt[(d0 + 2) * 128 + (j ^ 16)] = (unsigned short)(a.y & 0xFFFF);
    vt[(d0 + 3) * 128 + (j ^ 24)] = (unsigned short)(a.y >> 16);
    vt[(d0 + 4) * 128 + (j ^ 32)] = (unsigned short)(a.z & 0xFFFF);
    vt[(d0 + 5) * 128 + (j ^ 40)] = (unsigned short)(a.z >> 16);
    vt[(d0 + 6) * 128 + (j ^ 48)] = (unsigned short)(a.w & 0xFFFF);
    vt[(d0 + 7) * 128 + (j ^ 56)] = (unsigned short)(a.w >> 16);
  }
}

// ---------------- MFMA attention, strip-span formulation ----------------
__launch_bounds__(512, 2)
__global__ void k_attn(const unsigned short* __restrict__ Pbf, const float* __restrict__ ipb,
                       float* __restrict__ accg) {
  __shared__ __align__(16) unsigned short Pq[159 * 64];   // raw Q-proj span, swizzle blk d^((t&7)<<3)
  __shared__ __align__(16) unsigned short Pk[159 * 64];
  __shared__ __align__(16) unsigned short Vt[2][64 * 128]; // V^T window, swizzle j^((d&7)<<3)
  __shared__ __align__(16) unsigned short Ab[128 * 128];   // A'' window, swizzle j^((i&7)<<3)
  __shared__ __align__(16) float accs[159 * 68];           // stride 68: 16B-aligned rows
  __shared__ float hth[128];
  __shared__ float bB[160];
  __shared__ float bqS[64];

  const int strip = blockIdx.x, hd = blockIdx.y, v = blockIdx.z;
  const int l0 = strip * SW;
  const int nw = (SW < LWIN - l0) ? SW : (LWIN - l0);
  const int span = nw - 1 + WIN_;
  const int tid = threadIdx.x;
  const int lane = tid & 63, wv = tid >> 6;
  const int li16 = lane & 15, q4 = lane >> 4;
  const int iw = 16 * wv + li16;          // this thread's output row i (window-local)

  for (int i = tid; i < 159 * 68; i += 512) accs[i] = 0.0f;
  if (tid < 128) hth[tid] = hannf(tid);
  if (tid < 64) bqS[tid] = ipb[hd * 64 + tid];
  // stage raw Pq/Pk spans
  for (int i = tid; i < span * 8; i += 512) {
    int t = i >> 3, dg = i & 7;
    int row = prow(v, l0 + t);
    const unsigned short* src = Pbf + (size_t)row * 768 + hd * 64;
    uint4 q = *(const uint4*)(src + dg * 8);
    uint4 k = *(const uint4*)(src + 256 + dg * 8);
    int off = (dg * 8) ^ ((t & 7) << 3);
    *(uint4*)&Pq[t * 64 + off] = q;
    *(uint4*)&Pk[t * 64 + off] = k;
  }
  __syncthreads();

  // bias-dot array b(t) = bq·Pk(t)   (i-constant terms cancel in softmax)
  for (int p = tid; p < span; p += 512) {
    float b = 0.0f;
    int sw = (p & 7) << 3;
    for (int d = 0; d < 64; ++d) b += bqS[d] * bfu(Pk[p * 64 + (d ^ sw)]);
    bB[p] = b;
  }
  stage_v(Pbf, &Vt[0][0], v, hd, l0, tid);
  __syncthreads();

  // per-thread hann registers: hj8[m] = h(j)/8 at j = 16*(m>>2) + 4*q4 + (m&3)
  float hj8[32];
  #pragma unroll
  for (int tj = 0; tj < 8; ++tj)
    #pragma unroll
    for (int r = 0; r < 4; ++r) hj8[tj * 4 + r] = hth[16 * tj + 4 * q4 + r] * 0.125f;
  const float h_i = hth[iw];

  #pragma unroll 1
  for (int w = 0; w < nw; ++w) {
    // ---- S^T[j][i] = sum_d Pk[w+j][d] * Pq[w+i][d]  (raw Gram) ----
    bf16x8 Qf[2];
    {
      int t = w + iw, sw = (t & 7) << 3;
      Qf[0] = *(bf16x8*)&Pq[t * 64 + ((8 * q4) ^ sw)];
      Qf[1] = *(bf16x8*)&Pq[t * 64 + ((32 + 8 * q4) ^ sw)];
    }
    f32x4 S[8];
    #pragma unroll
    for (int tj = 0; tj < 8; ++tj) S[tj] = (f32x4){0.f, 0.f, 0.f, 0.f};
    #pragma unroll
    for (int tj = 0; tj < 8; ++tj) {
      int t = w + 16 * tj + li16, sw = (t & 7) << 3;
      bf16x8 Kf0 = *(bf16x8*)&Pk[t * 64 + ((8 * q4) ^ sw)];
      bf16x8 Kf1 = *(bf16x8*)&Pk[t * 64 + ((32 + 8 * q4) ^ sw)];
      S[tj] = __builtin_amdgcn_mfma_f32_16x16x32_bf16(Kf0, Qf[0], S[tj], 0, 0, 0);
      S[tj] = __builtin_amdgcn_mfma_f32_16x16x32_bf16(Kf1, Qf[1], S[tj], 0, 0, 0);
    }

    // ---- corrections + max-subtract softmax over j (NaN-proof) ----
    float mx = -3.0e38f;
    #pragma unroll
    for (int tj = 0; tj < 8; ++tj)
      #pragma unroll
      for (int r = 0; r < 4; ++r) {
        int j = 16 * tj + 4 * q4 + r;
        float s = hj8[tj * 4 + r] * fmaf(h_i, S[tj][r], bB[w + j]);
        S[tj][r] = s;
        mx = fmaxf(mx, s);
      }
    mx = fmaxf(mx, __shfl_xor(mx, 16));
    mx = fmaxf(mx, __shfl_xor(mx, 32));
    float sum = 0.0f;
    #pragma unroll
    for (int tj = 0; tj < 8; ++tj)
      #pragma unroll
      for (int r = 0; r < 4; ++r) {
        float e = __expf(S[tj][r] - mx);
        S[tj][r] = e;
        sum += e;
      }
    sum += __shfl_xor(sum, 16);
    sum += __shfl_xor(sum, 32);
    const float sc = 8.0f / sum;   // applied at accumulate; recovers h(j) scale

    // ---- A''[i][j] = e * h(j)/8, bf16-trunc into Ab (wave-private rows) ----
    {
      int sw = (iw & 7) << 3;
      #pragma unroll
      for (int tj = 0; tj < 8; ++tj) {
        uint2 o;
        o.x = pk2t(S[tj][0] * hj8[tj * 4 + 0], S[tj][1] * hj8[tj * 4 + 1]);
        o.y = pk2t(S[tj][2] * hj8[tj * 4 + 2], S[tj][3] * hj8[tj * 4 + 3]);
        *(uint2*)&Ab[iw * 128 + ((16 * tj + 4 * q4) ^ sw)] = o;
      }
    }

    // ---- O^T[d][i] = sum_j Vt[d][j] * A''[i][j] ----
    f32x4 O[4];
    #pragma unroll
    for (int mt = 0; mt < 4; ++mt) O[mt] = (f32x4){0.f, 0.f, 0.f, 0.f};
    const unsigned short* vt = &Vt[w & 1][0];
    {
      int swi = (iw & 7) << 3;
      #pragma unroll
      for (int ks = 0; ks < 4; ++ks) {
        bf16x8 Bf = *(bf16x8*)&Ab[iw * 128 + ((32 * ks + 8 * q4) ^ swi)];
        #pragma unroll
        for (int mt = 0; mt < 4; ++mt) {
          int d = 16 * mt + li16;
          bf16x8 Af = *(bf16x8*)&vt[d * 128 + ((32 * ks + 8 * q4) ^ ((d & 7) << 3))];
          O[mt] = __builtin_amdgcn_mfma_f32_16x16x32_bf16(Af, Bf, O[mt], 0, 0, 0);
        }
      }
    }

    // ---- accumulate O^T * sc into strip overlap-add buffer (vector RMW, race-free ownership) ----
    {
      float* arow = &accs[(w + iw) * 68];
      #pragma unroll
      for (int mt = 0; mt < 4; ++mt) {
        int c = 16 * mt + 4 * q4;
        float4 cur = *(float4*)&arow[c];
        cur.x += O[mt][0] * sc; cur.y += O[mt][1] * sc;
        cur.z += O[mt][2] * sc; cur.w += O[mt][3] * sc;
        *(float4*)&arow[c] = cur;
      }
    }

    if (w + 1 < nw) stage_v(Pbf, &Vt[(w + 1) & 1][0], v, hd, l0 + w + 1, tid);
    __syncthreads();
  }

  // ---- epilogue: + cnt*bv, atomic into global ----
  float* av = accg + (size_t)v * TPAD * CDIM;
  for (int i = tid; i < span * 64; i += 512) {
    int p = i >> 6, dd = i & 63;
    int lo = p - 127; if (lo < 0) lo = 0;
    int hi = p; if (hi > nw - 1) hi = nw - 1;
    float cnt = (float)(hi - lo + 1);
    float bvd = ipb[512 + hd * 64 + dd];
    atomicAdd(&av[(size_t)(l0 + p) * CDIM + hd * 64 + dd],
              accs[p * 68 + dd] + cnt * bvd);
  }
}

// ---------------- combine variants + merged projection (MFMA) ----------------
__launch_bounds__(512, 1)
__global__ void k_comb(const float* __restrict__ accg, const unsigned short* __restrict__ Mtb,
                       const float* __restrict__ vbv, const float* __restrict__ pb,
                       float* __restrict__ z, float* __restrict__ msum) {
  __shared__ __align__(16) unsigned short Ub[128 * 264];  // u-tile bf16, padded stride
  __shared__ float cfA[128], cfB[128], bscL[128];
  __shared__ float msB[256];
  const int tid = threadIdx.x;
  const int lane = tid & 63, wv = tid >> 6;
  const int li16 = lane & 15, q4 = lane >> 4;
  const int tw = wv & 1, ew = wv >> 1;
  const int t0 = blockIdx.x * 128;
  const int e0 = blockIdx.y * 128;

  if (tid < 128) {
    int s = t0 + tid;
    float c0 = countf(PADL + s);
    float c1 = countf(PADL + ((s + 64) & (TLEN - 1)));
    float fA = 0.5f / (c0 + 1e-6f), fB = 0.5f / (c1 + 1e-6f);
    cfA[tid] = fA; cfB[tid] = fB;
    bscL[tid] = c0 * fA + c1 * fB;
  }
  if (tid < 256) msB[tid] = 0.0f;
  __syncthreads();

  // build u-tile: u = 0.5*(a0/c0 + a1/c1), bf16
  for (int i = tid; i < 128 * 128; i += 512) {
    int rr = i >> 7, c2 = (i & 127) * 2;
    int s = t0 + rr;
    int s1 = (s + 64) & (TLEN - 1);
    float2 a0 = *(const float2*)&accg[(size_t)(PADL + s) * CDIM + c2];
    float2 a1 = *(const float2*)&accg[(size_t)TPAD * CDIM + (size_t)(PADL + s1) * CDIM + c2];
    float fA = cfA[rr], fB = cfB[rr];
    *(unsigned int*)&Ub[rr * 264 + c2] =
        pk2t(a0.x * fA + a1.x * fB, a0.y * fA + a1.y * fB);
  }
  __syncthreads();

  // GEMM: z[t][e] = sum_c u[t][c] * M[e][c]
  f32x4 acc[4][2];
  #pragma unroll
  for (int it = 0; it < 4; ++it)
    #pragma unroll
    for (int et = 0; et < 2; ++et) acc[it][et] = (f32x4){0.f, 0.f, 0.f, 0.f};
  #pragma unroll
  for (int ks = 0; ks < 8; ++ks) {
    bf16x8 Af[4], Bf[2];
    #pragma unroll
    for (int it = 0; it < 4; ++it)
      Af[it] = *(bf16x8*)&Ub[(tw * 64 + 16 * it + li16) * 264 + ks * 32 + q4 * 8];
    #pragma unroll
    for (int et = 0; et < 2; ++et)
      Bf[et] = *(const bf16x8*)(Mtb + (size_t)(e0 + ew * 32 + 16 * et + li16) * 256 + ks * 32 + q4 * 8);
    #pragma unroll
    for (int it = 0; it < 4; ++it)
      #pragma unroll
      for (int et = 0; et < 2; ++et)
        acc[it][et] = __builtin_amdgcn_mfma_f32_16x16x32_bf16(Af[it], Bf[et], acc[it][et], 0, 0, 0);
  }

  // epilogue + msum
  #pragma unroll
  for (int et = 0; et < 2; ++et) {
    int e = e0 + ew * 32 + 16 * et + li16;
    float vbe = vbv[e], pbe = pb[e];
    float part = 0.0f;
    #pragma unroll
    for (int it = 0; it < 4; ++it)
      #pragma unroll
      for (int r = 0; r < 4; ++r) {
        int rloc = tw * 64 + 16 * it + 4 * q4 + r;
        float val = acc[it][et][r] + bscL[rloc] * vbe + pbe;
        z[(size_t)(t0 + rloc) * CDIM + e] = val;
        part += val;
      }
    atomicAdd(&msB[e - e0 + (e0 & 128)], part);
  }
  __syncthreads();
  if (tid < 128) atomicAdd(&msum[e0 + tid], msB[tid + (e0 & 128)]);
}

// ---------------- SE gate (parallel) ----------------
__global__ void k_se(const float* __restrict__ msum, const float* __restrict__ w1,
                     const float* __restrict__ w2, float* __restrict__ gate) {
  __shared__ float red2[16][4];
  __shared__ float s1[16];
  int tid = threadIdx.x;
  int lane = tid & 63, wv = tid >> 6;
  float sm = msum[tid] * (1.0f / 1024.0f);
  #pragma unroll
  for (int r = 0; r < 16; ++r) {
    float v = sm * w1[(size_t)r * 256 + tid];
    #pragma unroll
    for (int m = 32; m >= 1; m >>= 1) v += __shfl_xor(v, m);
    if (lane == 0) red2[r][wv] = v;
  }
  __syncthreads();
  if (tid < 16) {
    float a = red2[tid][0] + red2[tid][1] + red2[tid][2] + red2[tid][3];
    s1[tid] = fmaxf(a, 0.0f);
  }
  __syncthreads();
  float gacc = 0.0f;
  #pragma unroll
  for (int i = 0; i < 16; ++i) gacc += s1[i] * w2[(size_t)tid * 16 + i];
  gate[tid] = 1.0f / (1.0f + __expf(-gacc));
}

// ---------------- out = x + z * gate ----------------
__global__ void k_final(const float* __restrict__ x, const float* __restrict__ z,
                        const float* __restrict__ gate, float* __restrict__ out) {
  int i = blockIdx.x * 256 + threadIdx.x;
  float4 xv = ((const float4*)x)[i];
  float4 zv = ((const float4*)z)[i];
  float4 gv = ((const float4*)gate)[i & 63];
  float4 o;
  o.x = xv.x + zv.x * gv.x;
  o.y = xv.y + zv.y * gv.y;
  o.z = xv.z + zv.z * gv.z;
  o.w = xv.w + zv.w * gv.w;
  ((float4*)out)[i] = o;
}

extern "C" void kernel_launch(void* const* d_in, const int* in_sizes, int n_in,
                              void* d_out, int out_size, void* d_ws, size_t ws_size,
                              hipStream_t stream) {
  const float* x   = (const float*)d_in[0];
  const float* lng = (const float*)d_in[1];
  const float* lnb = (const float*)d_in[2];
  const float* ipw = (const float*)d_in[3];
  const float* ipb = (const float*)d_in[4];
  const float* ow  = (const float*)d_in[5];
  const float* ob  = (const float*)d_in[6];
  const float* pw  = (const float*)d_in[7];
  const float* pb  = (const float*)d_in[8];
  const float* w1  = (const float*)d_in[9];
  const float* w2  = (const float*)d_in[10];
  float* out = (float*)d_out;

  float* ws = (float*)d_ws;
  unsigned short* lnbf = (unsigned short*)ws;             // 1024*256 us = 131072 f
  unsigned short* Wb   = (unsigned short*)(ws + 131072);  // 768*256  us = 98304 f
  unsigned short* Pbf  = (unsigned short*)(ws + 229376);  // 1150*768 us = 441600 f
  float* accg = ws + 229376 + 441600;                     // 2*1150*256 = 588800 f
  unsigned short* Mtb = (unsigned short*)(accg + 588800); // 256*256 us = 32768 f
  float* vbv  = accg + 588800 + 32768;                    // 256
  float* z    = vbv + 256;                                // 262144
  float* msum = z + 262144;                               // 256
  float* gate = msum + 256;                               // 256

  hipMemsetAsync(Pbf, 0, (size_t)TPAD * 768 * sizeof(unsigned short), stream);
  hipMemsetAsync(accg, 0, (size_t)2 * TPAD * CDIM * sizeof(float), stream);
  hipMemsetAsync(msum, 0, CDIM * sizeof(float), stream);

  k_ln<<<dim3(TLEN / 4), dim3(256), 0, stream>>>(x, lng, lnb, lnbf);
  k_castw<<<dim3(96), dim3(256), 0, stream>>>(ipw, Wb);
  k_proj<<<dim3(8, 6), dim3(512), 0, stream>>>(lnbf, Wb, Pbf);
  k_mmat<<<dim3(256), dim3(256), 0, stream>>>(pw, ow, ob, Mtb, vbv);
  k_attn<<<dim3(32, NHEAD, 2), dim3(512), 0, stream>>>(Pbf, ipb, accg);
  k_comb<<<dim3(8, 2), dim3(512), 0, stream>>>(accg, Mtb, vbv, pb, z, msum);
  k_se<<<dim3(1), dim3(256), 0, stream>>>(msum, w1, w2, gate);
  k_final<<<dim3(256), dim3(256), 0, stream>>>(x, z, gate, out);
}

// Round 8
// 213.547 us; speedup vs baseline: 2.5364x; 1.0486x over previous
//
#include <hip/hip_runtime.h>

#define TLEN 1024
#define CDIM 256
#define NHEAD 4
#define HD 64
#define WIN_ 128
#define PADL 63
#define LWIN 1023
#define TPAD 1150
#define SW 32        // windows per strip: 32 strips x 4 heads x 2 variants = 256 blocks

typedef __attribute__((ext_vector_type(8))) short bf16x8;
typedef __attribute__((ext_vector_type(4))) float f32x4;

__device__ __forceinline__ int prow(int v, int t) {
  if (v == 0) return t;
  if (t < PADL || t >= PADL + TLEN) return t;
  int s = t - PADL;
  s = (s + (TLEN - 64)) & (TLEN - 1);   // roll(x, +64)
  return PADL + s;
}

__device__ __forceinline__ float hannf(int j) {
  return 0.5f * (1.0f - __cosf(6.283185307179586f * (float)j / 127.0f));
}

__device__ __forceinline__ float countf(int t) {
  int lo = t - 127; if (lo < 0) lo = 0;
  int hi = t;       if (hi > LWIN - 1) hi = LWIN - 1;
  return (float)(hi - lo + 1);
}

__device__ __forceinline__ unsigned short bfr(float f) {  // fp32 -> bf16 RTNE
  unsigned int u = __float_as_uint(f);
  u += 0x7FFFu + ((u >> 16) & 1u);
  return (unsigned short)(u >> 16);
}
// pack two f32 -> bf16x2 by truncation, single v_perm_b32
__device__ __forceinline__ unsigned int pk2t(float a, float b) {
  return __builtin_amdgcn_perm(__float_as_uint(b), __float_as_uint(a), 0x07060302u);
}
__device__ __forceinline__ float bfu(unsigned short u) {
  return __uint_as_float(((unsigned int)u) << 16);
}

// ---------------- fused prep: LN->bf16 | castw | mmat | zero accg | zero Pbf pads+msum ----------------
// Block-role partition on blockIdx only (uniform branches, no cross-block deps).
__global__ void k_prep(const float* __restrict__ x, const float* __restrict__ g,
                       const float* __restrict__ b, unsigned short* __restrict__ lnbf,
                       const float* __restrict__ W, unsigned short* __restrict__ Wb,
                       const float* __restrict__ pw, const float* __restrict__ ow,
                       const float* __restrict__ ob, unsigned short* __restrict__ Mtb,
                       float* __restrict__ vbv,
                       float* __restrict__ accg, unsigned short* __restrict__ Pbf,
                       float* __restrict__ msum) {
  __shared__ float pr[256];
  __shared__ float red[256];
  const int bid = blockIdx.x;
  const int tid = threadIdx.x;
  if (bid < 256) {
    // ---- LayerNorm -> bf16, 4 rows/block ----
    int wv = tid >> 6, lane = tid & 63;
    int r = bid * 4 + wv;
    float4 v = ((const float4*)(x + (size_t)r * CDIM))[lane];
    float s = v.x + v.y + v.z + v.w;
    float q = v.x * v.x + v.y * v.y + v.z * v.z + v.w * v.w;
    #pragma unroll
    for (int m = 32; m >= 1; m >>= 1) { s += __shfl_xor(s, m); q += __shfl_xor(q, m); }
    float mu = s * (1.0f / 256.0f);
    float var = q * (1.0f / 256.0f) - mu * mu;
    float rs = rsqrtf(var + 1e-5f);
    float4 gg = ((const float4*)g)[lane];
    float4 bb = ((const float4*)b)[lane];
    uint2 o;
    o.x = (unsigned int)bfr((v.x - mu) * rs * gg.x + bb.x) |
          ((unsigned int)bfr((v.y - mu) * rs * gg.y + bb.y) << 16);
    o.y = (unsigned int)bfr((v.z - mu) * rs * gg.z + bb.z) |
          ((unsigned int)bfr((v.w - mu) * rs * gg.w + bb.w) << 16);
    ((uint2*)(lnbf + (size_t)r * CDIM))[lane] = o;
  } else if (bid < 352) {
    // ---- cast in_proj_w -> bf16 ----
    int i = (bid - 256) * 256 + tid;   // 8 elems each, 96 blocks
    const float4* src = (const float4*)W;
    float4 a = src[2 * i], c = src[2 * i + 1];
    uint4 o;
    o.x = (unsigned int)bfr(a.x) | ((unsigned int)bfr(a.y) << 16);
    o.y = (unsigned int)bfr(a.z) | ((unsigned int)bfr(a.w) << 16);
    o.z = (unsigned int)bfr(c.x) | ((unsigned int)bfr(c.y) << 16);
    o.w = (unsigned int)bfr(c.z) | ((unsigned int)bfr(c.w) << 16);
    ((uint4*)Wb)[i] = o;
  } else if (bid < 608) {
    // ---- merged M[e] = pw[e]·ow (bf16); vbv[e] = pw[e]·ob ----
    const int e = bid - 352;
    pr[tid] = pw[(size_t)e * CDIM + tid];
    __syncthreads();
    float a0 = 0.f, a1 = 0.f, a2 = 0.f, a3 = 0.f;
    for (int m = 0; m < 256; m += 4) {
      a0 += pr[m] * ow[(size_t)m * CDIM + tid];
      a1 += pr[m + 1] * ow[(size_t)(m + 1) * CDIM + tid];
      a2 += pr[m + 2] * ow[(size_t)(m + 2) * CDIM + tid];
      a3 += pr[m + 3] * ow[(size_t)(m + 3) * CDIM + tid];
    }
    Mtb[(size_t)e * CDIM + tid] = bfr((a0 + a1) + (a2 + a3));
    red[tid] = pr[tid] * ob[tid];
    __syncthreads();
    for (int s = 128; s > 0; s >>= 1) { if (tid < s) red[tid] += red[tid + s]; __syncthreads(); }
    if (tid == 0) vbv[e] = red[0];
  } else if (bid < 624) {
    // ---- zero accg: 2*1150*256 f = 147200 uint4 ----
    uint4 zz = make_uint4(0, 0, 0, 0);
    for (int i = (bid - 608) * 256 + tid; i < 147200; i += 16 * 256)
      ((uint4*)accg)[i] = zz;
  } else {
    // ---- zero Pbf pad rows (0..62, 1087..1149) + msum ----
    uint4 zz = make_uint4(0, 0, 0, 0);
    for (int i = (bid - 624) * 256 + tid; i < 12096; i += 16 * 256) {
      int idx = (i < 6048) ? i : (104352 + (i - 6048));   // 63*768/8 = 6048; 1087*768/8 = 104352
      ((uint4*)Pbf)[idx] = zz;
    }
    if (bid == 624 && tid < 64) ((float4*)msum)[tid] = make_float4(0.f, 0.f, 0.f, 0.f);
  }
}

// ---------------- P projection via MFMA: P[63+s][e] = ln[s]·W[e] ----------------
__launch_bounds__(512, 1)
__global__ void k_proj(const unsigned short* __restrict__ lnbf,
                       const unsigned short* __restrict__ Wb,
                       unsigned short* __restrict__ Pbf) {
  const int tid = threadIdx.x;
  const int lane = tid & 63, wv = tid >> 6;
  const int li16 = lane & 15, q4 = lane >> 4;
  const int ws = wv & 1, we = wv >> 1;
  const int s0 = blockIdx.x * 128 + ws * 64;
  const int e0 = blockIdx.y * 128 + we * 32;

  f32x4 acc[4][2];
  #pragma unroll
  for (int it = 0; it < 4; ++it)
    #pragma unroll
    for (int et = 0; et < 2; ++et) acc[it][et] = (f32x4){0.f, 0.f, 0.f, 0.f};

  #pragma unroll
  for (int ks = 0; ks < 8; ++ks) {
    bf16x8 Af[4], Bf[2];
    #pragma unroll
    for (int it = 0; it < 4; ++it)
      Af[it] = *(const bf16x8*)(lnbf + (size_t)(s0 + 16 * it + li16) * 256 + ks * 32 + q4 * 8);
    #pragma unroll
    for (int et = 0; et < 2; ++et)
      Bf[et] = *(const bf16x8*)(Wb + (size_t)(e0 + 16 * et + li16) * 256 + ks * 32 + q4 * 8);
    #pragma unroll
    for (int it = 0; it < 4; ++it)
      #pragma unroll
      for (int et = 0; et < 2; ++et)
        acc[it][et] = __builtin_amdgcn_mfma_f32_16x16x32_bf16(Af[it], Bf[et], acc[it][et], 0, 0, 0);
  }
  #pragma unroll
  for (int it = 0; it < 4; ++it)
    #pragma unroll
    for (int et = 0; et < 2; ++et)
      #pragma unroll
      for (int r = 0; r < 4; ++r) {
        int srow = s0 + 16 * it + 4 * q4 + r;
        int e = e0 + 16 * et + li16;
        Pbf[(size_t)(PADL + srow) * 768 + e] = bfr(acc[it][et][r]);
      }
}

// ---------------- V window staging: global -> LDS transposed (scalar, proven) ----------------
__device__ __forceinline__ void stage_v(const unsigned short* __restrict__ Pbf,
                                        unsigned short* vt, int v, int hd,
                                        int trow0, int tid) {
  int j = tid & 127, dgsel = tid >> 7;
  int row = prow(v, trow0 + j);
  const unsigned short* base = Pbf + (size_t)row * 768 + 512 + hd * 64;
  #pragma unroll
  for (int pass = 0; pass < 2; ++pass) {
    int dg = dgsel + 4 * pass;
    uint4 a = *(const uint4*)(base + dg * 8);
    int d0 = dg * 8;
    vt[(d0 + 0) * 128 + (j ^ 0)]  = (unsigned short)(a.x & 0xFFFF);
    vt[(d0 + 1) * 128 + (j ^ 8)]  = (unsigned short)(a.x >> 16);
    vt[(d0 + 2) * 128 + (j ^ 16)] = (unsigned short)(a.y & 0xFFFF);
    vt[(d0 + 3) * 128 + (j ^ 24)] = (unsigned short)(a.y >> 16);
    vt[(d0 + 4) * 128 + (j ^ 32)] = (unsigned short)(a.z & 0xFFFF);
    vt[(d0 + 5) * 128 + (j ^ 40)] = (unsigned short)(a.z >> 16);
    vt[(d0 + 6) * 128 + (j ^ 48)] = (unsigned short)(a.w & 0xFFFF);
    vt[(d0 + 7) * 128 + (j ^ 56)] = (unsigned short)(a.w >> 16);
  }
}

// ---------------- MFMA attention, strip-span formulation ----------------
__launch_bounds__(512, 2)
__global__ void k_attn(const unsigned short* __restrict__ Pbf, const float* __restrict__ ipb,
                       float* __restrict__ accg) {
  __shared__ __align__(16) unsigned short Pq[159 * 64];   // raw Q-proj span, swizzle blk d^((t&7)<<3)
  __shared__ __align__(16) unsigned short Pk[159 * 64];
  __shared__ __align__(16) unsigned short Vt[2][64 * 128]; // V^T window, swizzle j^((d&7)<<3)
  __shared__ __align__(16) unsigned short Ab[128 * 128];   // A'' window, swizzle j^((i&7)<<3)
  __shared__ __align__(16) float accs[159 * 68];           // stride 68: 16B-aligned rows
  __shared__ float hth[128];
  __shared__ float bB[160];
  __shared__ float bqS[64];

  const int strip = blockIdx.x, hd = blockIdx.y, v = blockIdx.z;
  const int l0 = strip * SW;
  const int nw = (SW < LWIN - l0) ? SW : (LWIN - l0);
  const int span = nw - 1 + WIN_;
  const int tid = threadIdx.x;
  const int lane = tid & 63, wv = tid >> 6;
  const int li16 = lane & 15, q4 = lane >> 4;
  const int iw = 16 * wv + li16;          // this thread's output row i (window-local)

  for (int i = tid; i < 159 * 68; i += 512) accs[i] = 0.0f;
  if (tid < 128) hth[tid] = hannf(tid);
  if (tid < 64) bqS[tid] = ipb[hd * 64 + tid];
  // stage raw Pq/Pk spans
  for (int i = tid; i < span * 8; i += 512) {
    int t = i >> 3, dg = i & 7;
    int row = prow(v, l0 + t);
    const unsigned short* src = Pbf + (size_t)row * 768 + hd * 64;
    uint4 q = *(const uint4*)(src + dg * 8);
    uint4 k = *(const uint4*)(src + 256 + dg * 8);
    int off = (dg * 8) ^ ((t & 7) << 3);
    *(uint4*)&Pq[t * 64 + off] = q;
    *(uint4*)&Pk[t * 64 + off] = k;
  }
  __syncthreads();

  // bias-dot array b(t) = bq·Pk(t)   (i-constant terms cancel in softmax)
  for (int p = tid; p < span; p += 512) {
    float b = 0.0f;
    int sw = (p & 7) << 3;
    for (int d = 0; d < 64; ++d) b += bqS[d] * bfu(Pk[p * 64 + (d ^ sw)]);
    bB[p] = b;
  }
  stage_v(Pbf, &Vt[0][0], v, hd, l0, tid);
  __syncthreads();

  // per-thread hann registers: hj8[m] = h(j)/8 at j = 16*(m>>2) + 4*q4 + (m&3)
  float hj8[32];
  #pragma unroll
  for (int tj = 0; tj < 8; ++tj)
    #pragma unroll
    for (int r = 0; r < 4; ++r) hj8[tj * 4 + r] = hth[16 * tj + 4 * q4 + r] * 0.125f;
  const float h_i = hth[iw];

  #pragma unroll 1
  for (int w = 0; w < nw; ++w) {
    // ---- S^T[j][i] = sum_d Pk[w+j][d] * Pq[w+i][d]  (raw Gram) ----
    bf16x8 Qf[2];
    {
      int t = w + iw, sw = (t & 7) << 3;
      Qf[0] = *(bf16x8*)&Pq[t * 64 + ((8 * q4) ^ sw)];
      Qf[1] = *(bf16x8*)&Pq[t * 64 + ((32 + 8 * q4) ^ sw)];
    }
    f32x4 S[8];
    #pragma unroll
    for (int tj = 0; tj < 8; ++tj) S[tj] = (f32x4){0.f, 0.f, 0.f, 0.f};
    #pragma unroll
    for (int tj = 0; tj < 8; ++tj) {
      int t = w + 16 * tj + li16, sw = (t & 7) << 3;
      bf16x8 Kf0 = *(bf16x8*)&Pk[t * 64 + ((8 * q4) ^ sw)];
      bf16x8 Kf1 = *(bf16x8*)&Pk[t * 64 + ((32 + 8 * q4) ^ sw)];
      S[tj] = __builtin_amdgcn_mfma_f32_16x16x32_bf16(Kf0, Qf[0], S[tj], 0, 0, 0);
      S[tj] = __builtin_amdgcn_mfma_f32_16x16x32_bf16(Kf1, Qf[1], S[tj], 0, 0, 0);
    }

    // ---- corrections + max-subtract softmax over j (NaN-proof) ----
    float mx = -3.0e38f;
    #pragma unroll
    for (int tj = 0; tj < 8; ++tj)
      #pragma unroll
      for (int r = 0; r < 4; ++r) {
        int j = 16 * tj + 4 * q4 + r;
        float s = hj8[tj * 4 + r] * fmaf(h_i, S[tj][r], bB[w + j]);
        S[tj][r] = s;
        mx = fmaxf(mx, s);
      }
    mx = fmaxf(mx, __shfl_xor(mx, 16));
    mx = fmaxf(mx, __shfl_xor(mx, 32));
    float sum = 0.0f;
    #pragma unroll
    for (int tj = 0; tj < 8; ++tj)
      #pragma unroll
      for (int r = 0; r < 4; ++r) {
        float e = __expf(S[tj][r] - mx);
        S[tj][r] = e;
        sum += e;
      }
    sum += __shfl_xor(sum, 16);
    sum += __shfl_xor(sum, 32);
    const float sc = 8.0f / sum;   // applied at accumulate; recovers h(j) scale

    // ---- A''[i][j] = e * h(j)/8, bf16-trunc into Ab (wave-private rows) ----
    {
      int sw = (iw & 7) << 3;
      #pragma unroll
      for (int tj = 0; tj < 8; ++tj) {
        uint2 o;
        o.x = pk2t(S[tj][0] * hj8[tj * 4 + 0], S[tj][1] * hj8[tj * 4 + 1]);
        o.y = pk2t(S[tj][2] * hj8[tj * 4 + 2], S[tj][3] * hj8[tj * 4 + 3]);
        *(uint2*)&Ab[iw * 128 + ((16 * tj + 4 * q4) ^ sw)] = o;
      }
    }

    // ---- O^T[d][i] = sum_j Vt[d][j] * A''[i][j] ----
    f32x4 O[4];
    #pragma unroll
    for (int mt = 0; mt < 4; ++mt) O[mt] = (f32x4){0.f, 0.f, 0.f, 0.f};
    const unsigned short* vt = &Vt[w & 1][0];
    {
      int swi = (iw & 7) << 3;
      #pragma unroll
      for (int ks = 0; ks < 4; ++ks) {
        bf16x8 Bf = *(bf16x8*)&Ab[iw * 128 + ((32 * ks + 8 * q4) ^ swi)];
        #pragma unroll
        for (int mt = 0; mt < 4; ++mt) {
          int d = 16 * mt + li16;
          bf16x8 Af = *(bf16x8*)&vt[d * 128 + ((32 * ks + 8 * q4) ^ ((d & 7) << 3))];
          O[mt] = __builtin_amdgcn_mfma_f32_16x16x32_bf16(Af, Bf, O[mt], 0, 0, 0);
        }
      }
    }

    // ---- accumulate O^T * sc into strip overlap-add buffer (vector RMW, race-free ownership) ----
    {
      float* arow = &accs[(w + iw) * 68];
      #pragma unroll
      for (int mt = 0; mt < 4; ++mt) {
        int c = 16 * mt + 4 * q4;
        float4 cur = *(float4*)&arow[c];
        cur.x += O[mt][0] * sc; cur.y += O[mt][1] * sc;
        cur.z += O[mt][2] * sc; cur.w += O[mt][3] * sc;
        *(float4*)&arow[c] = cur;
      }
    }

    if (w + 1 < nw) stage_v(Pbf, &Vt[(w + 1) & 1][0], v, hd, l0 + w + 1, tid);
    __syncthreads();
  }

  // ---- epilogue: + cnt*bv, atomic into global ----
  float* av = accg + (size_t)v * TPAD * CDIM;
  for (int i = tid; i < span * 64; i += 512) {
    int p = i >> 6, dd = i & 63;
    int lo = p - 127; if (lo < 0) lo = 0;
    int hi = p; if (hi > nw - 1) hi = nw - 1;
    float cnt = (float)(hi - lo + 1);
    float bvd = ipb[512 + hd * 64 + dd];
    atomicAdd(&av[(size_t)(l0 + p) * CDIM + hd * 64 + dd],
              accs[p * 68 + dd] + cnt * bvd);
  }
}

// ---------------- combine variants + merged projection (MFMA) ----------------
__launch_bounds__(512, 1)
__global__ void k_comb(const float* __restrict__ accg, const unsigned short* __restrict__ Mtb,
                       const float* __restrict__ vbv, const float* __restrict__ pb,
                       float* __restrict__ z, float* __restrict__ msum) {
  __shared__ __align__(16) unsigned short Ub[128 * 264];  // u-tile bf16, padded stride
  __shared__ float cfA[128], cfB[128], bscL[128];
  __shared__ float msB[256];
  const int tid = threadIdx.x;
  const int lane = tid & 63, wv = tid >> 6;
  const int li16 = lane & 15, q4 = lane >> 4;
  const int tw = wv & 1, ew = wv >> 1;
  const int t0 = blockIdx.x * 128;
  const int e0 = blockIdx.y * 128;

  if (tid < 128) {
    int s = t0 + tid;
    float c0 = countf(PADL + s);
    float c1 = countf(PADL + ((s + 64) & (TLEN - 1)));
    float fA = 0.5f / (c0 + 1e-6f), fB = 0.5f / (c1 + 1e-6f);
    cfA[tid] = fA; cfB[tid] = fB;
    bscL[tid] = c0 * fA + c1 * fB;
  }
  if (tid < 256) msB[tid] = 0.0f;
  __syncthreads();

  // build u-tile: u = 0.5*(a0/c0 + a1/c1), bf16
  for (int i = tid; i < 128 * 128; i += 512) {
    int rr = i >> 7, c2 = (i & 127) * 2;
    int s = t0 + rr;
    int s1 = (s + 64) & (TLEN - 1);
    float2 a0 = *(const float2*)&accg[(size_t)(PADL + s) * CDIM + c2];
    float2 a1 = *(const float2*)&accg[(size_t)TPAD * CDIM + (size_t)(PADL + s1) * CDIM + c2];
    float fA = cfA[rr], fB = cfB[rr];
    *(unsigned int*)&Ub[rr * 264 + c2] =
        pk2t(a0.x * fA + a1.x * fB, a0.y * fA + a1.y * fB);
  }
  __syncthreads();

  // GEMM: z[t][e] = sum_c u[t][c] * M[e][c]
  f32x4 acc[4][2];
  #pragma unroll
  for (int it = 0; it < 4; ++it)
    #pragma unroll
    for (int et = 0; et < 2; ++et) acc[it][et] = (f32x4){0.f, 0.f, 0.f, 0.f};
  #pragma unroll
  for (int ks = 0; ks < 8; ++ks) {
    bf16x8 Af[4], Bf[2];
    #pragma unroll
    for (int it = 0; it < 4; ++it)
      Af[it] = *(bf16x8*)&Ub[(tw * 64 + 16 * it + li16) * 264 + ks * 32 + q4 * 8];
    #pragma unroll
    for (int et = 0; et < 2; ++et)
      Bf[et] = *(const bf16x8*)(Mtb + (size_t)(e0 + ew * 32 + 16 * et + li16) * 256 + ks * 32 + q4 * 8);
    #pragma unroll
    for (int it = 0; it < 4; ++it)
      #pragma unroll
      for (int et = 0; et < 2; ++et)
        acc[it][et] = __builtin_amdgcn_mfma_f32_16x16x32_bf16(Af[it], Bf[et], acc[it][et], 0, 0, 0);
  }

  // epilogue + msum
  #pragma unroll
  for (int et = 0; et < 2; ++et) {
    int e = e0 + ew * 32 + 16 * et + li16;
    float vbe = vbv[e], pbe = pb[e];
    float part = 0.0f;
    #pragma unroll
    for (int it = 0; it < 4; ++it)
      #pragma unroll
      for (int r = 0; r < 4; ++r) {
        int rloc = tw * 64 + 16 * it + 4 * q4 + r;
        float val = acc[it][et][r] + bscL[rloc] * vbe + pbe;
        z[(size_t)(t0 + rloc) * CDIM + e] = val;
        part += val;
      }
    atomicAdd(&msB[e - e0 + (e0 & 128)], part);
  }
  __syncthreads();
  if (tid < 128) atomicAdd(&msum[e0 + tid], msB[tid + (e0 & 128)]);
}

// ---------------- fused SE gate + residual: out = x + z * sigmoid(SE(mean z)) ----------------
__global__ void k_finalse(const float* __restrict__ x, const float* __restrict__ z,
                          const float* __restrict__ msum, const float* __restrict__ w1,
                          const float* __restrict__ w2, float* __restrict__ out) {
  __shared__ float red2[16][4];
  __shared__ float s1[16];
  __shared__ float gateS[256];
  int tid = threadIdx.x;
  int lane = tid & 63, wv = tid >> 6;
  float sm = msum[tid] * (1.0f / 1024.0f);
  #pragma unroll
  for (int r = 0; r < 16; ++r) {
    float v = sm * w1[(size_t)r * 256 + tid];
    #pragma unroll
    for (int m = 32; m >= 1; m >>= 1) v += __shfl_xor(v, m);
    if (lane == 0) red2[r][wv] = v;
  }
  __syncthreads();
  if (tid < 16) {
    float a = red2[tid][0] + red2[tid][1] + red2[tid][2] + red2[tid][3];
    s1[tid] = fmaxf(a, 0.0f);
  }
  __syncthreads();
  float gacc = 0.0f;
  #pragma unroll
  for (int i = 0; i < 16; ++i) gacc += s1[i] * w2[(size_t)tid * 16 + i];
  gateS[tid] = 1.0f / (1.0f + __expf(-gacc));
  __syncthreads();
  int i = blockIdx.x * 256 + tid;
  float4 xv = ((const float4*)x)[i];
  float4 zv = ((const float4*)z)[i];
  float4 gv = ((const float4*)gateS)[i & 63];
  float4 o;
  o.x = xv.x + zv.x * gv.x;
  o.y = xv.y + zv.y * gv.y;
  o.z = xv.z + zv.z * gv.z;
  o.w = xv.w + zv.w * gv.w;
  ((float4*)out)[i] = o;
}

extern "C" void kernel_launch(void* const* d_in, const int* in_sizes, int n_in,
                              void* d_out, int out_size, void* d_ws, size_t ws_size,
                              hipStream_t stream) {
  const float* x   = (const float*)d_in[0];
  const float* lng = (const float*)d_in[1];
  const float* lnb = (const float*)d_in[2];
  const float* ipw = (const float*)d_in[3];
  const float* ipb = (const float*)d_in[4];
  const float* ow  = (const float*)d_in[5];
  const float* ob  = (const float*)d_in[6];
  const float* pw  = (const float*)d_in[7];
  const float* pb  = (const float*)d_in[8];
  const float* w1  = (const float*)d_in[9];
  const float* w2  = (const float*)d_in[10];
  float* out = (float*)d_out;

  float* ws = (float*)d_ws;
  unsigned short* lnbf = (unsigned short*)ws;             // 1024*256 us = 131072 f
  unsigned short* Wb   = (unsigned short*)(ws + 131072);  // 768*256  us = 98304 f
  unsigned short* Pbf  = (unsigned short*)(ws + 229376);  // 1150*768 us = 441600 f
  float* accg = ws + 229376 + 441600;                     // 2*1150*256 = 588800 f
  unsigned short* Mtb = (unsigned short*)(accg + 588800); // 256*256 us = 32768 f
  float* vbv  = accg + 588800 + 32768;                    // 256
  float* z    = vbv + 256;                                // 262144
  float* msum = z + 262144;                               // 256

  k_prep<<<dim3(640), dim3(256), 0, stream>>>(x, lng, lnb, lnbf, ipw, Wb,
                                              pw, ow, ob, Mtb, vbv, accg, Pbf, msum);
  k_proj<<<dim3(8, 6), dim3(512), 0, stream>>>(lnbf, Wb, Pbf);
  k_attn<<<dim3(32, NHEAD, 2), dim3(512), 0, stream>>>(Pbf, ipb, accg);
  k_comb<<<dim3(8, 2), dim3(512), 0, stream>>>(accg, Mtb, vbv, pb, z, msum);
  k_finalse<<<dim3(256), dim3(256), 0, stream>>>(x, z, msum, w1, w2, out);
}

// Round 9
// 207.245 us; speedup vs baseline: 2.6135x; 1.0304x over previous
//
#include <hip/hip_runtime.h>

#define TLEN 1024
#define CDIM 256
#define NHEAD 4
#define HD 64
#define WIN_ 128
#define PADL 63
#define LWIN 1023
#define TPAD 1150
#define SW 32        // windows per strip: 32 strips x 4 heads x 2 variants = 256 blocks

typedef __attribute__((ext_vector_type(8))) short bf16x8;
typedef __attribute__((ext_vector_type(4))) float f32x4;

__device__ __forceinline__ int prow(int v, int t) {
  if (v == 0) return t;
  if (t < PADL || t >= PADL + TLEN) return t;
  int s = t - PADL;
  s = (s + (TLEN - 64)) & (TLEN - 1);   // roll(x, +64)
  return PADL + s;
}

__device__ __forceinline__ float hannf(int j) {
  return 0.5f * (1.0f - __cosf(6.283185307179586f * (float)j / 127.0f));
}

__device__ __forceinline__ float countf(int t) {
  int lo = t - 127; if (lo < 0) lo = 0;
  int hi = t;       if (hi > LWIN - 1) hi = LWIN - 1;
  return (float)(hi - lo + 1);
}

__device__ __forceinline__ unsigned short bfr(float f) {  // fp32 -> bf16 RTNE
  unsigned int u = __float_as_uint(f);
  u += 0x7FFFu + ((u >> 16) & 1u);
  return (unsigned short)(u >> 16);
}
// pack two f32 -> bf16x2 by truncation, single v_perm_b32
__device__ __forceinline__ unsigned int pk2t(float a, float b) {
  return __builtin_amdgcn_perm(__float_as_uint(b), __float_as_uint(a), 0x07060302u);
}
__device__ __forceinline__ float bfu(unsigned short u) {
  return __uint_as_float(((unsigned int)u) << 16);
}
__device__ __forceinline__ float bflo(unsigned int u) { return __uint_as_float(u << 16); }
__device__ __forceinline__ float bfhi(unsigned int u) { return __uint_as_float(u & 0xFFFF0000u); }

// ---------------- fused prep: LN->bf16 | castw | mmat | zero accg | zero Pbf pads+msum ----------------
__global__ void k_prep(const float* __restrict__ x, const float* __restrict__ g,
                       const float* __restrict__ b, unsigned short* __restrict__ lnbf,
                       const float* __restrict__ W, unsigned short* __restrict__ Wb,
                       const float* __restrict__ pw, const float* __restrict__ ow,
                       const float* __restrict__ ob, unsigned short* __restrict__ Mtb,
                       float* __restrict__ vbv,
                       float* __restrict__ accg, unsigned short* __restrict__ Pbf,
                       float* __restrict__ msum) {
  __shared__ float pr[256];
  __shared__ float red[256];
  const int bid = blockIdx.x;
  const int tid = threadIdx.x;
  if (bid < 256) {
    int wv = tid >> 6, lane = tid & 63;
    int r = bid * 4 + wv;
    float4 v = ((const float4*)(x + (size_t)r * CDIM))[lane];
    float s = v.x + v.y + v.z + v.w;
    float q = v.x * v.x + v.y * v.y + v.z * v.z + v.w * v.w;
    #pragma unroll
    for (int m = 32; m >= 1; m >>= 1) { s += __shfl_xor(s, m); q += __shfl_xor(q, m); }
    float mu = s * (1.0f / 256.0f);
    float var = q * (1.0f / 256.0f) - mu * mu;
    float rs = rsqrtf(var + 1e-5f);
    float4 gg = ((const float4*)g)[lane];
    float4 bb = ((const float4*)b)[lane];
    uint2 o;
    o.x = (unsigned int)bfr((v.x - mu) * rs * gg.x + bb.x) |
          ((unsigned int)bfr((v.y - mu) * rs * gg.y + bb.y) << 16);
    o.y = (unsigned int)bfr((v.z - mu) * rs * gg.z + bb.z) |
          ((unsigned int)bfr((v.w - mu) * rs * gg.w + bb.w) << 16);
    ((uint2*)(lnbf + (size_t)r * CDIM))[lane] = o;
  } else if (bid < 352) {
    int i = (bid - 256) * 256 + tid;
    const float4* src = (const float4*)W;
    float4 a = src[2 * i], c = src[2 * i + 1];
    uint4 o;
    o.x = (unsigned int)bfr(a.x) | ((unsigned int)bfr(a.y) << 16);
    o.y = (unsigned int)bfr(a.z) | ((unsigned int)bfr(a.w) << 16);
    o.z = (unsigned int)bfr(c.x) | ((unsigned int)bfr(c.y) << 16);
    o.w = (unsigned int)bfr(c.z) | ((unsigned int)bfr(c.w) << 16);
    ((uint4*)Wb)[i] = o;
  } else if (bid < 608) {
    const int e = bid - 352;
    pr[tid] = pw[(size_t)e * CDIM + tid];
    __syncthreads();
    float a0 = 0.f, a1 = 0.f, a2 = 0.f, a3 = 0.f;
    for (int m = 0; m < 256; m += 4) {
      a0 += pr[m] * ow[(size_t)m * CDIM + tid];
      a1 += pr[m + 1] * ow[(size_t)(m + 1) * CDIM + tid];
      a2 += pr[m + 2] * ow[(size_t)(m + 2) * CDIM + tid];
      a3 += pr[m + 3] * ow[(size_t)(m + 3) * CDIM + tid];
    }
    Mtb[(size_t)e * CDIM + tid] = bfr((a0 + a1) + (a2 + a3));
    red[tid] = pr[tid] * ob[tid];
    __syncthreads();
    for (int s = 128; s > 0; s >>= 1) { if (tid < s) red[tid] += red[tid + s]; __syncthreads(); }
    if (tid == 0) vbv[e] = red[0];
  } else if (bid < 624) {
    uint4 zz = make_uint4(0, 0, 0, 0);
    for (int i = (bid - 608) * 256 + tid; i < 147200; i += 16 * 256)
      ((uint4*)accg)[i] = zz;
  } else {
    uint4 zz = make_uint4(0, 0, 0, 0);
    for (int i = (bid - 624) * 256 + tid; i < 12096; i += 16 * 256) {
      int idx = (i < 6048) ? i : (104352 + (i - 6048));
      ((uint4*)Pbf)[idx] = zz;
    }
    if (bid == 624 && tid < 64) ((float4*)msum)[tid] = make_float4(0.f, 0.f, 0.f, 0.f);
  }
}

// ---------------- P projection via MFMA ----------------
__launch_bounds__(512, 1)
__global__ void k_proj(const unsigned short* __restrict__ lnbf,
                       const unsigned short* __restrict__ Wb,
                       unsigned short* __restrict__ Pbf) {
  const int tid = threadIdx.x;
  const int lane = tid & 63, wv = tid >> 6;
  const int li16 = lane & 15, q4 = lane >> 4;
  const int ws = wv & 1, we = wv >> 1;
  const int s0 = blockIdx.x * 128 + ws * 64;
  const int e0 = blockIdx.y * 128 + we * 32;

  f32x4 acc[4][2];
  #pragma unroll
  for (int it = 0; it < 4; ++it)
    #pragma unroll
    for (int et = 0; et < 2; ++et) acc[it][et] = (f32x4){0.f, 0.f, 0.f, 0.f};

  #pragma unroll
  for (int ks = 0; ks < 8; ++ks) {
    bf16x8 Af[4], Bf[2];
    #pragma unroll
    for (int it = 0; it < 4; ++it)
      Af[it] = *(const bf16x8*)(lnbf + (size_t)(s0 + 16 * it + li16) * 256 + ks * 32 + q4 * 8);
    #pragma unroll
    for (int et = 0; et < 2; ++et)
      Bf[et] = *(const bf16x8*)(Wb + (size_t)(e0 + 16 * et + li16) * 256 + ks * 32 + q4 * 8);
    #pragma unroll
    for (int it = 0; it < 4; ++it)
      #pragma unroll
      for (int et = 0; et < 2; ++et)
        acc[it][et] = __builtin_amdgcn_mfma_f32_16x16x32_bf16(Af[it], Bf[et], acc[it][et], 0, 0, 0);
  }
  #pragma unroll
  for (int it = 0; it < 4; ++it)
    #pragma unroll
    for (int et = 0; et < 2; ++et)
      #pragma unroll
      for (int r = 0; r < 4; ++r) {
        int srow = s0 + 16 * it + 4 * q4 + r;
        int e = e0 + 16 * et + li16;
        Pbf[(size_t)(PADL + srow) * 768 + e] = bfr(acc[it][et][r]);
      }
}

// ---------------- V' staging: V'[j][d] = E(j)*h_j*Pv; row 64 = E(j); j-paired b32 writes ----------------
__device__ __forceinline__ void stage_v(const unsigned short* __restrict__ Pbf,
                                        unsigned short* vt, int v, int hd,
                                        int l0, int w, int tid,
                                        const float* __restrict__ bB,
                                        const float* __restrict__ hth) {
  const int jp = tid & 63;
  const int dg = tid >> 6;         // 0..7
  const int j0 = 2 * jp;
  const int p0 = w + j0;
  int row0 = prow(v, l0 + w + j0);
  int row1 = prow(v, l0 + w + j0 + 1);
  uint4 a = *(const uint4*)(Pbf + (size_t)row0 * 768 + 512 + hd * 64 + dg * 8);
  uint4 b = *(const uint4*)(Pbf + (size_t)row1 * 768 + 512 + hd * 64 + dg * 8);
  float h0 = hth[j0], h1 = hth[j0 + 1];
  float e0 = __expf(h0 * bB[p0] * 0.125f);
  float e1 = __expf(h1 * bB[p0 + 1] * 0.125f);
  float f0 = e0 * h0, f1 = e1 * h1;
  unsigned int av[4] = {a.x, a.y, a.z, a.w};
  unsigned int bv[4] = {b.x, b.y, b.z, b.w};
  #pragma unroll
  for (int q = 0; q < 4; ++q) {
    int d0 = dg * 8 + 2 * q;
    unsigned int w0 = pk2t(f0 * bflo(av[q]), f1 * bflo(bv[q]));
    unsigned int w1 = pk2t(f0 * bfhi(av[q]), f1 * bfhi(bv[q]));
    *(unsigned int*)&vt[d0 * 128 + (j0 ^ ((d0 & 7) << 3))] = w0;
    *(unsigned int*)&vt[(d0 + 1) * 128 + (j0 ^ (((d0 + 1) & 7) << 3))] = w1;
  }
  if (dg == 0) {   // E row at d=64 (swizzle (64&7)<<3 = 0)
    *(unsigned int*)&vt[64 * 128 + j0] = pk2t(e0, e1);
  }
}

// ---------------- MFMA attention ----------------
__launch_bounds__(512, 2)
__global__ void k_attn(const unsigned short* __restrict__ Pbf, const float* __restrict__ ipb,
                       float* __restrict__ accg) {
  __shared__ __align__(16) unsigned short Pq[159 * 64];    // swizzle blk d^((t&7)<<3)
  __shared__ __align__(16) unsigned short Pk[159 * 64];
  __shared__ __align__(16) unsigned short Vt[2][80 * 128]; // rows 0..63 V', 64 E, 65..79 zero
  __shared__ __align__(16) unsigned short Ab[128 * 128];   // A''=exp, swizzle j^((i&7)<<3)
  __shared__ __align__(16) float accs[159 * 68];
  __shared__ float hth[128];
  __shared__ float bB[160];
  __shared__ float bqS[64];

  const int strip = blockIdx.x, hd = blockIdx.y, v = blockIdx.z;
  const int l0 = strip * SW;
  const int nw = (SW < LWIN - l0) ? SW : (LWIN - l0);
  const int span = nw - 1 + WIN_;
  const int tid = threadIdx.x;
  const int lane = tid & 63, wv = tid >> 6;
  const int li16 = lane & 15, q4 = lane >> 4;
  const int iw = 16 * wv + li16;

  for (int i = tid; i < 159 * 68; i += 512) accs[i] = 0.0f;
  if (tid < 128) hth[tid] = hannf(tid);
  if (tid < 64) bqS[tid] = ipb[hd * 64 + tid];
  for (int i = tid; i < span * 8; i += 512) {
    int t = i >> 3, dg = i & 7;
    int row = prow(v, l0 + t);
    const unsigned short* src = Pbf + (size_t)row * 768 + hd * 64;
    uint4 q = *(const uint4*)(src + dg * 8);
    uint4 k = *(const uint4*)(src + 256 + dg * 8);
    int off = (dg * 8) ^ ((t & 7) << 3);
    *(uint4*)&Pq[t * 64 + off] = q;
    *(uint4*)&Pk[t * 64 + off] = k;
  }
  // zero Vt pad rows 65..79 of both buffers (240 uint4 each)
  {
    uint4 zz = make_uint4(0, 0, 0, 0);
    for (int i = tid; i < 480; i += 512) {
      int bidx = i / 240, k = i % 240;
      *(uint4*)&Vt[bidx][65 * 128 + k * 8] = zz;
    }
  }
  __syncthreads();

  // bias-dot array b(t) = bq·Pk(t)
  for (int p = tid; p < span; p += 512) {
    float b = 0.0f;
    int sw = (p & 7) << 3;
    for (int d = 0; d < 64; ++d) b += bqS[d] * bfu(Pk[p * 64 + (d ^ sw)]);
    bB[p] = b;
  }
  __syncthreads();          // bB ready before stage_v reads it
  stage_v(Pbf, &Vt[0][0], v, hd, l0, 0, tid, bB, hth);
  __syncthreads();

  // per-thread hh[m] = h_i * h_j(m) / 8
  float hh[32];
  {
    const float h_i = hth[iw];
    #pragma unroll
    for (int tj = 0; tj < 8; ++tj)
      #pragma unroll
      for (int r = 0; r < 4; ++r)
        hh[tj * 4 + r] = h_i * hth[16 * tj + 4 * q4 + r] * 0.125f;
  }

  #pragma unroll 1
  for (int w = 0; w < nw; ++w) {
    // ---- S^T[j][i] = Pk[w+j]·Pq[w+i] (raw Gram) ----
    bf16x8 Qf[2];
    {
      int t = w + iw, sw = (t & 7) << 3;
      Qf[0] = *(bf16x8*)&Pq[t * 64 + ((8 * q4) ^ sw)];
      Qf[1] = *(bf16x8*)&Pq[t * 64 + ((32 + 8 * q4) ^ sw)];
    }
    f32x4 S[8];
    #pragma unroll
    for (int tj = 0; tj < 8; ++tj) S[tj] = (f32x4){0.f, 0.f, 0.f, 0.f};
    #pragma unroll
    for (int tj = 0; tj < 8; ++tj) {
      int t = w + 16 * tj + li16, sw = (t & 7) << 3;
      bf16x8 Kf0 = *(bf16x8*)&Pk[t * 64 + ((8 * q4) ^ sw)];
      bf16x8 Kf1 = *(bf16x8*)&Pk[t * 64 + ((32 + 8 * q4) ^ sw)];
      S[tj] = __builtin_amdgcn_mfma_f32_16x16x32_bf16(Kf0, Qf[0], S[tj], 0, 0, 0);
      S[tj] = __builtin_amdgcn_mfma_f32_16x16x32_bf16(Kf1, Qf[1], S[tj], 0, 0, 0);
    }

    // ---- A'' = exp(hh*S)  (|hh*S| < ~1: no max-subtract needed; E/h_j folded into V') ----
    #pragma unroll
    for (int tj = 0; tj < 8; ++tj)
      #pragma unroll
      for (int r = 0; r < 4; ++r)
        S[tj][r] = __expf(hh[tj * 4 + r] * S[tj][r]);

    // ---- pack raw exp into Ab (wave-private rows) ----
    {
      int sw = (iw & 7) << 3;
      #pragma unroll
      for (int tj = 0; tj < 8; ++tj) {
        uint2 o;
        o.x = pk2t(S[tj][0], S[tj][1]);
        o.y = pk2t(S[tj][2], S[tj][3]);
        *(uint2*)&Ab[iw * 128 + ((16 * tj + 4 * q4) ^ sw)] = o;
      }
    }

    // ---- O'^T[d][i] = sum_j V'[d][j]*A''[i][j]; tile mt=4 yields normalizer (E row) ----
    f32x4 O[5];
    #pragma unroll
    for (int mt = 0; mt < 5; ++mt) O[mt] = (f32x4){0.f, 0.f, 0.f, 0.f};
    const unsigned short* vt = &Vt[w & 1][0];
    {
      int swi = (iw & 7) << 3;
      #pragma unroll
      for (int ks = 0; ks < 4; ++ks) {
        bf16x8 Bf = *(bf16x8*)&Ab[iw * 128 + ((32 * ks + 8 * q4) ^ swi)];
        #pragma unroll
        for (int mt = 0; mt < 5; ++mt) {
          int d = 16 * mt + li16;
          bf16x8 Af = *(bf16x8*)&vt[d * 128 + ((32 * ks + 8 * q4) ^ ((d & 7) << 3))];
          O[mt] = __builtin_amdgcn_mfma_f32_16x16x32_bf16(Af, Bf, O[mt], 0, 0, 0);
        }
      }
    }

    // ---- normalizer: row 64 value lives at lane li16 (q4=0), reg 0 of tile 4 ----
    float nn = __shfl(O[4][0], li16);
    float sc = 1.0f / nn;

    // ---- accumulate O^T * sc (vector RMW, race-free ownership) ----
    {
      float* arow = &accs[(w + iw) * 68];
      #pragma unroll
      for (int mt = 0; mt < 4; ++mt) {
        int c = 16 * mt + 4 * q4;
        float4 cur = *(float4*)&arow[c];
        cur.x += O[mt][0] * sc; cur.y += O[mt][1] * sc;
        cur.z += O[mt][2] * sc; cur.w += O[mt][3] * sc;
        *(float4*)&arow[c] = cur;
      }
    }

    if (w + 1 < nw) stage_v(Pbf, &Vt[(w + 1) & 1][0], v, hd, l0, w + 1, tid, bB, hth);
    __syncthreads();
  }

  // ---- epilogue: + cnt*bv, atomic into global ----
  float* av = accg + (size_t)v * TPAD * CDIM;
  for (int i = tid; i < span * 64; i += 512) {
    int p = i >> 6, dd = i & 63;
    int lo = p - 127; if (lo < 0) lo = 0;
    int hi = p; if (hi > nw - 1) hi = nw - 1;
    float cnt = (float)(hi - lo + 1);
    float bvd = ipb[512 + hd * 64 + dd];
    atomicAdd(&av[(size_t)(l0 + p) * CDIM + hd * 64 + dd],
              accs[p * 68 + dd] + cnt * bvd);
  }
}

// ---------------- combine variants + merged projection (MFMA) ----------------
__launch_bounds__(512, 1)
__global__ void k_comb(const float* __restrict__ accg, const unsigned short* __restrict__ Mtb,
                       const float* __restrict__ vbv, const float* __restrict__ pb,
                       float* __restrict__ z, float* __restrict__ msum) {
  __shared__ __align__(16) unsigned short Ub[128 * 264];
  __shared__ float cfA[128], cfB[128], bscL[128];
  __shared__ float msB[256];
  const int tid = threadIdx.x;
  const int lane = tid & 63, wv = tid >> 6;
  const int li16 = lane & 15, q4 = lane >> 4;
  const int tw = wv & 1, ew = wv >> 1;
  const int t0 = blockIdx.x * 128;
  const int e0 = blockIdx.y * 128;

  if (tid < 128) {
    int s = t0 + tid;
    float c0 = countf(PADL + s);
    float c1 = countf(PADL + ((s + 64) & (TLEN - 1)));
    float fA = 0.5f / (c0 + 1e-6f), fB = 0.5f / (c1 + 1e-6f);
    cfA[tid] = fA; cfB[tid] = fB;
    bscL[tid] = c0 * fA + c1 * fB;
  }
  if (tid < 256) msB[tid] = 0.0f;
  __syncthreads();

  for (int i = tid; i < 128 * 128; i += 512) {
    int rr = i >> 7, c2 = (i & 127) * 2;
    int s = t0 + rr;
    int s1 = (s + 64) & (TLEN - 1);
    float2 a0 = *(const float2*)&accg[(size_t)(PADL + s) * CDIM + c2];
    float2 a1 = *(const float2*)&accg[(size_t)TPAD * CDIM + (size_t)(PADL + s1) * CDIM + c2];
    float fA = cfA[rr], fB = cfB[rr];
    *(unsigned int*)&Ub[rr * 264 + c2] =
        pk2t(a0.x * fA + a1.x * fB, a0.y * fA + a1.y * fB);
  }
  __syncthreads();

  f32x4 acc[4][2];
  #pragma unroll
  for (int it = 0; it < 4; ++it)
    #pragma unroll
    for (int et = 0; et < 2; ++et) acc[it][et] = (f32x4){0.f, 0.f, 0.f, 0.f};
  #pragma unroll
  for (int ks = 0; ks < 8; ++ks) {
    bf16x8 Af[4], Bf[2];
    #pragma unroll
    for (int it = 0; it < 4; ++it)
      Af[it] = *(bf16x8*)&Ub[(tw * 64 + 16 * it + li16) * 264 + ks * 32 + q4 * 8];
    #pragma unroll
    for (int et = 0; et < 2; ++et)
      Bf[et] = *(const bf16x8*)(Mtb + (size_t)(e0 + ew * 32 + 16 * et + li16) * 256 + ks * 32 + q4 * 8);
    #pragma unroll
    for (int it = 0; it < 4; ++it)
      #pragma unroll
      for (int et = 0; et < 2; ++et)
        acc[it][et] = __builtin_amdgcn_mfma_f32_16x16x32_bf16(Af[it], Bf[et], acc[it][et], 0, 0, 0);
  }

  #pragma unroll
  for (int et = 0; et < 2; ++et) {
    int e = e0 + ew * 32 + 16 * et + li16;
    float vbe = vbv[e], pbe = pb[e];
    float part = 0.0f;
    #pragma unroll
    for (int it = 0; it < 4; ++it)
      #pragma unroll
      for (int r = 0; r < 4; ++r) {
        int rloc = tw * 64 + 16 * it + 4 * q4 + r;
        float val = acc[it][et][r] + bscL[rloc] * vbe + pbe;
        z[(size_t)(t0 + rloc) * CDIM + e] = val;
        part += val;
      }
    atomicAdd(&msB[e - e0 + (e0 & 128)], part);
  }
  __syncthreads();
  if (tid < 128) atomicAdd(&msum[e0 + tid], msB[tid + (e0 & 128)]);
}

// ---------------- fused SE gate + residual ----------------
__global__ void k_finalse(const float* __restrict__ x, const float* __restrict__ z,
                          const float* __restrict__ msum, const float* __restrict__ w1,
                          const float* __restrict__ w2, float* __restrict__ out) {
  __shared__ float red2[16][4];
  __shared__ float s1[16];
  __shared__ float gateS[256];
  int tid = threadIdx.x;
  int lane = tid & 63, wv = tid >> 6;
  float sm = msum[tid] * (1.0f / 1024.0f);
  #pragma unroll
  for (int r = 0; r < 16; ++r) {
    float v = sm * w1[(size_t)r * 256 + tid];
    #pragma unroll
    for (int m = 32; m >= 1; m >>= 1) v += __shfl_xor(v, m);
    if (lane == 0) red2[r][wv] = v;
  }
  __syncthreads();
  if (tid < 16) {
    float a = red2[tid][0] + red2[tid][1] + red2[tid][2] + red2[tid][3];
    s1[tid] = fmaxf(a, 0.0f);
  }
  __syncthreads();
  float gacc = 0.0f;
  #pragma unroll
  for (int i = 0; i < 16; ++i) gacc += s1[i] * w2[(size_t)tid * 16 + i];
  gateS[tid] = 1.0f / (1.0f + __expf(-gacc));
  __syncthreads();
  int i = blockIdx.x * 256 + tid;
  float4 xv = ((const float4*)x)[i];
  float4 zv = ((const float4*)z)[i];
  float4 gv = ((const float4*)gateS)[i & 63];
  float4 o;
  o.x = xv.x + zv.x * gv.x;
  o.y = xv.y + zv.y * gv.y;
  o.z = xv.z + zv.z * gv.z;
  o.w = xv.w + zv.w * gv.w;
  ((float4*)out)[i] = o;
}

extern "C" void kernel_launch(void* const* d_in, const int* in_sizes, int n_in,
                              void* d_out, int out_size, void* d_ws, size_t ws_size,
                              hipStream_t stream) {
  const float* x   = (const float*)d_in[0];
  const float* lng = (const float*)d_in[1];
  const float* lnb = (const float*)d_in[2];
  const float* ipw = (const float*)d_in[3];
  const float* ipb = (const float*)d_in[4];
  const float* ow  = (const float*)d_in[5];
  const float* ob  = (const float*)d_in[6];
  const float* pw  = (const float*)d_in[7];
  const float* pb  = (const float*)d_in[8];
  const float* w1  = (const float*)d_in[9];
  const float* w2  = (const float*)d_in[10];
  float* out = (float*)d_out;

  float* ws = (float*)d_ws;
  unsigned short* lnbf = (unsigned short*)ws;             // 131072 f
  unsigned short* Wb   = (unsigned short*)(ws + 131072);  // 98304 f
  unsigned short* Pbf  = (unsigned short*)(ws + 229376);  // 441600 f
  float* accg = ws + 229376 + 441600;                     // 588800 f
  unsigned short* Mtb = (unsigned short*)(accg + 588800); // 32768 f
  float* vbv  = accg + 588800 + 32768;                    // 256
  float* z    = vbv + 256;                                // 262144
  float* msum = z + 262144;                               // 256

  k_prep<<<dim3(640), dim3(256), 0, stream>>>(x, lng, lnb, lnbf, ipw, Wb,
                                              pw, ow, ob, Mtb, vbv, accg, Pbf, msum);
  k_proj<<<dim3(8, 6), dim3(512), 0, stream>>>(lnbf, Wb, Pbf);
  k_attn<<<dim3(32, NHEAD, 2), dim3(512), 0, stream>>>(Pbf, ipb, accg);
  k_comb<<<dim3(8, 2), dim3(512), 0, stream>>>(accg, Mtb, vbv, pb, z, msum);
  k_finalse<<<dim3(256), dim3(256), 0, stream>>>(x, z, msum, w1, w2, out);
}